// Round 5
// baseline (912.572 us; speedup 1.0000x reference)
//
#include <hip/hip_runtime.h>
#include <hip/hip_bf16.h>
#include <cstdint>

#define S_LEN 2048
#define HIDDEN 2560
#define NH 32
#define NKV 8
#define HD 128
#define GS 128

typedef __attribute__((ext_vector_type(8))) short short8v;  // 8 x bf16 frag
typedef __attribute__((ext_vector_type(4))) float f32x4;
typedef unsigned int uint;
typedef unsigned short ushort;

__device__ inline ushort f2bf(float f) {
    uint u = __builtin_bit_cast(uint, f);
    u += 0x7fffu + ((u >> 16) & 1u);   // RNE
    return (ushort)(u >> 16);
}
__device__ inline float bf2f(ushort u) {
    return __builtin_bit_cast(float, (uint)u << 16);
}
__device__ inline uint pk2(ushort a, ushort b) { return (uint)a | ((uint)b << 16); }

// async global->LDS, 16B per lane; lds base must be wave-uniform
__device__ __attribute__((always_inline)) inline void gl_lds16(const void* g, void* l) {
    __builtin_amdgcn_global_load_lds(
        (const __attribute__((address_space(1))) unsigned int*)g,
        (__attribute__((address_space(3))) unsigned int*)l, 16, 0, 0);
}

// ---------------------------------------------------------------------------
// X -> hi/lo bf16 split (once; all GEMM tiles then stage via global_load_lds)
// ---------------------------------------------------------------------------
__global__ __launch_bounds__(256) void xsplit_kernel(
    const float* __restrict__ X, ushort* __restrict__ Xhi, ushort* __restrict__ Xlo)
{
    int i = (blockIdx.x * 256 + threadIdx.x) * 4;
    float4 v = *(const float4*)&X[i];
    ushort h0 = f2bf(v.x), h1 = f2bf(v.y), h2 = f2bf(v.z), h3 = f2bf(v.w);
    uint2 hw = {pk2(h0, h1), pk2(h2, h3)};
    uint2 lw = {pk2(f2bf(v.x - bf2f(h0)), f2bf(v.y - bf2f(h1))),
                pk2(f2bf(v.z - bf2f(h2)), f2bf(v.w - bf2f(h3)))};
    *(uint2*)&Xhi[i] = hw;
    *(uint2*)&Xlo[i] = lw;
}

// ---------------------------------------------------------------------------
// Fused Q/K/V AWQ-int4 MFMA GEMM + RoPE epilogue.
// B values = (nib + 128): EXACT bf16 via 0x4300+n (pure int ops, no f2bf).
// Correction: y = sc*(gacc - (z+128)*rowsum), rowsum via all-ones-B MFMA.
// A staged hi/lo bf16 from precomputed Xhi/Xlo via global_load_lds
// (linear LDS dest + inverse-swizzled global source; read swz ^((m&7)<<4)).
// Grid x: [0,32) Q | [32,40) K | [40,48) V; y: 16 m-bands of 128.
// Epilogue: Q/K -> bias+rope (fp32) -> hi/lo bf16 stores; V -> bf16 [N][M].
// ---------------------------------------------------------------------------
__global__ __launch_bounds__(256) void qkv_mfma_kernel(
    const ushort* __restrict__ Xhi, const ushort* __restrict__ Xlo,
    const int* __restrict__ q_qw, const float* __restrict__ q_sc,
    const int* __restrict__ q_qz, const float* __restrict__ q_b,
    const int* __restrict__ k_qw, const float* __restrict__ k_sc,
    const int* __restrict__ k_qz, const float* __restrict__ k_b,
    const int* __restrict__ v_qw, const float* __restrict__ v_sc,
    const int* __restrict__ v_qz, const float* __restrict__ v_b,
    const float* __restrict__ cosb, const float* __restrict__ sinb,
    ushort* __restrict__ Qhi, ushort* __restrict__ Qlo,
    ushort* __restrict__ Khi, ushort* __restrict__ Klo,
    ushort* __restrict__ VbfT)
{
    __shared__ ushort Ahi[128 * 64];   // 16 KB, [m][k] swz ^((m&7)<<4)
    __shared__ ushort Alo[128 * 64];
    __shared__ ushort Bt[128 * 64];    // [n][k] swz ^((n&7)<<4)

    const int t  = threadIdx.x;
    const int w  = t >> 6;
    const int l  = t & 63;
    const int lg = l >> 4;
    const int lr = l & 15;
    const int bx = blockIdx.x;
    const int m0 = blockIdx.y * 128;
    const int K  = HIDDEN;

    int region, nbase, Nw;
    const int* QW; const float* SC; const int* QZ; const float* BI;
    if (bx < 32)      { region = 0; nbase = bx * 128;        Nw = NH * HD;
                        QW = q_qw; SC = q_sc; QZ = q_qz; BI = q_b; }
    else if (bx < 40) { region = 1; nbase = (bx - 32) * 128; Nw = NKV * HD;
                        QW = k_qw; SC = k_sc; QZ = k_qz; BI = k_b; }
    else              { region = 2; nbase = (bx - 40) * 128; Nw = NKV * HD;
                        QW = v_qw; SC = v_sc; QZ = v_qz; BI = v_b; }

    f32x4 macc[2][8];
#pragma unroll
    for (int mf = 0; mf < 2; ++mf)
#pragma unroll
        for (int nf = 0; nf < 8; ++nf) macc[mf][nf] = f32x4{0.f, 0.f, 0.f, 0.f};
    f32x4 gacc[2][8], os[2];
    const f32x4 zc = f32x4{0.f, 0.f, 0.f, 0.f};
    short8v ones;
#pragma unroll
    for (int j = 0; j < 8; ++j) ones[j] = (short)0x3F80;   // bf16 1.0

    const int ngroups = K / GS;
    for (int g = 0; g < ngroups; ++g) {
#pragma unroll
        for (int hf = 0; hf < 2; ++hf) {
            const int k0 = g * 128 + hf * 64;
            // ---- A stage: async copy hi/lo, pre-swizzled source ----
#pragma unroll
            for (int i = 0; i < 4; ++i) {
                int slot = w * 256 + i * 64 + l;
                int m = slot >> 3, c = slot & 7;
                size_t goff = (size_t)(m0 + m) * K + k0 + ((c ^ (m & 7)) * 8);
                char* ldst = (char*)Ahi + (w * 256 + i * 64) * 16;
                gl_lds16(Xhi + goff, ldst);
                gl_lds16(Xlo + goff, (char*)Alo + (w * 256 + i * 64) * 16);
            }
            // ---- B stage: nibble+128 exact bf16 (int ops only) ----
            const int g8 = k0 >> 3;
#pragma unroll
            for (int i = 0; i < 4; ++i) {
                int u = t + 256 * i;
                int krow = u >> 7, n = u & 127;
                uint q = (uint)QW[(size_t)(g8 + krow) * Nw + nbase + n];
                uint xA = q & 0x0F0F0F0Fu;
                uint xB = (q >> 4) & 0x0F0F0F0Fu;
                uint4 dw;
                dw.x = 0x43004300u | (xA & 0xFFu)         | ((xB & 0xFFu) << 16);
                dw.y = 0x43004300u | ((xA >> 8) & 0xFFu)  | (((xB >> 8) & 0xFFu) << 16);
                dw.z = 0x43004300u | ((xA >> 16) & 0xFFu) | (((xB >> 16) & 0xFFu) << 16);
                dw.w = 0x43004300u | (xA >> 24)           | ((xB >> 24) << 16);
                *(uint4*)((char*)Bt + ((n * 128 + krow * 16) ^ ((n & 7) << 4))) = dw;
            }
            __syncthreads();
            // ---- compute ----
#pragma unroll
            for (int ks = 0; ks < 2; ++ks) {
                short8v av[2], avl[2], bv[8];
#pragma unroll
                for (int mf = 0; mf < 2; ++mf) {
                    int m = w * 32 + mf * 16 + lr;
                    int off = (m * 128 + lg * 16 + ks * 64) ^ ((m & 7) << 4);
                    av[mf]  = *(const short8v*)((char*)Ahi + off);
                    avl[mf] = *(const short8v*)((char*)Alo + off);
                }
#pragma unroll
                for (int nf = 0; nf < 8; ++nf) {
                    int n = nf * 16 + lr;
                    bv[nf] = *(const short8v*)((char*)Bt +
                              ((n * 128 + lg * 16 + ks * 64) ^ ((n & 7) << 4)));
                }
                const bool first = (hf == 0 && ks == 0);
#pragma unroll
                for (int mf = 0; mf < 2; ++mf) {
                    f32x4 c0 = first ? zc : os[mf];
                    c0 = __builtin_amdgcn_mfma_f32_16x16x32_bf16(av[mf], ones, c0, 0, 0, 0);
                    c0 = __builtin_amdgcn_mfma_f32_16x16x32_bf16(avl[mf], ones, c0, 0, 0, 0);
                    os[mf] = c0;
#pragma unroll
                    for (int nf = 0; nf < 8; ++nf) {
                        f32x4 c = first ? zc : gacc[mf][nf];
                        c = __builtin_amdgcn_mfma_f32_16x16x32_bf16(av[mf], bv[nf], c, 0, 0, 0);
                        c = __builtin_amdgcn_mfma_f32_16x16x32_bf16(avl[mf], bv[nf], c, 0, 0, 0);
                        gacc[mf][nf] = c;
                    }
                }
            }
            __syncthreads();
        }
        // ---- group-end: macc += sc*gacc - sc*(z+128)*rowsum ----
#pragma unroll
        for (int nf = 0; nf < 8; ++nf) {
            int col = nbase + nf * 16 + lr;
            float sc = SC[(size_t)g * Nw + col];
            float sz = sc * ((float)QZ[(size_t)g * Nw + col] + 128.0f);
#pragma unroll
            for (int mf = 0; mf < 2; ++mf)
#pragma unroll
                for (int r = 0; r < 4; ++r)
                    macc[mf][nf][r] += sc * gacc[mf][nf][r] - sz * os[mf][r];
        }
    }

    // ---- epilogue: +bias, then per-region ----
#pragma unroll
    for (int nf = 0; nf < 8; ++nf) {
        float bv = BI[nbase + nf * 16 + lr];
#pragma unroll
        for (int mf = 0; mf < 2; ++mf)
#pragma unroll
            for (int r = 0; r < 4; ++r) macc[mf][nf][r] += bv;
    }
    if (region == 2) {
#pragma unroll
        for (int mf = 0; mf < 2; ++mf)
#pragma unroll
            for (int r = 0; r < 4; ++r) {
                int row = m0 + w * 32 + mf * 16 + lg * 4 + r;
#pragma unroll
                for (int nf = 0; nf < 8; ++nf)
                    VbfT[(size_t)(nbase + nf * 16 + lr) * S_LEN + row] = f2bf(macc[mf][nf][r]);
            }
    } else {
        ushort* OH = (region == 0) ? Qhi : Khi;
        ushort* OL = (region == 0) ? Qlo : Klo;
        const int No = (region == 0) ? NH * HD : NKV * HD;
        const float osc = (region == 0) ? 0.08838834764831845f : 1.0f;
#pragma unroll
        for (int mf = 0; mf < 2; ++mf)
#pragma unroll
            for (int r = 0; r < 4; ++r) {
                int row = m0 + w * 32 + mf * 16 + lg * 4 + r;
                const float* cb = &cosb[(size_t)row * HD];
                const float* sb = &sinb[(size_t)row * HD];
#pragma unroll
                for (int nf = 0; nf < 4; ++nf) {
                    int d = nf * 16 + lr;
                    float a = macc[mf][nf][r], b = macc[mf][nf + 4][r];
                    float o1 = (a * cb[d] - b * sb[d]) * osc;
                    float o2 = (b * cb[d + 64] + a * sb[d + 64]) * osc;
                    ushort h1 = f2bf(o1), h2 = f2bf(o2);
                    size_t base = (size_t)row * No + nbase + d;
                    OH[base] = h1;      OL[base] = f2bf(o1 - bf2f(h1));
                    OH[base + 64] = h2; OL[base + 64] = f2bf(o2 - bf2f(h2));
                }
            }
    }
}

// ---------------------------------------------------------------------------
// O-projection: X = AO bf16 (exact), same bias-trick GEMM, f32 out, no bias.
// ---------------------------------------------------------------------------
__global__ __launch_bounds__(256) void oproj_mfma_kernel(
    const ushort* __restrict__ Xb, const int* __restrict__ QW,
    const float* __restrict__ SC, const int* __restrict__ QZ,
    float* __restrict__ Y)
{
    const int K = NH * HD;     // 4096
    const int N = HIDDEN;      // 2560
    __shared__ ushort Ahi[128 * 64];
    __shared__ ushort Bt[128 * 64];

    const int t  = threadIdx.x;
    const int w  = t >> 6;
    const int l  = t & 63;
    const int lg = l >> 4;
    const int lr = l & 15;
    const int n0 = blockIdx.x * 128;
    const int m0 = blockIdx.y * 128;

    f32x4 macc[2][8];
#pragma unroll
    for (int mf = 0; mf < 2; ++mf)
#pragma unroll
        for (int nf = 0; nf < 8; ++nf) macc[mf][nf] = f32x4{0.f, 0.f, 0.f, 0.f};
    f32x4 gacc[2][8], os[2];
    const f32x4 zc = f32x4{0.f, 0.f, 0.f, 0.f};
    short8v ones;
#pragma unroll
    for (int j = 0; j < 8; ++j) ones[j] = (short)0x3F80;

    const int ngroups = K / GS;
    for (int g = 0; g < ngroups; ++g) {
#pragma unroll
        for (int hf = 0; hf < 2; ++hf) {
            const int k0 = g * 128 + hf * 64;
#pragma unroll
            for (int i = 0; i < 4; ++i) {
                int slot = w * 256 + i * 64 + l;
                int m = slot >> 3, c = slot & 7;
                size_t goff = (size_t)(m0 + m) * K + k0 + ((c ^ (m & 7)) * 8);
                gl_lds16(Xb + goff, (char*)Ahi + (w * 256 + i * 64) * 16);
            }
            const int g8 = k0 >> 3;
#pragma unroll
            for (int i = 0; i < 4; ++i) {
                int u = t + 256 * i;
                int krow = u >> 7, n = u & 127;
                uint q = (uint)QW[(size_t)(g8 + krow) * N + n0 + n];
                uint xA = q & 0x0F0F0F0Fu;
                uint xB = (q >> 4) & 0x0F0F0F0Fu;
                uint4 dw;
                dw.x = 0x43004300u | (xA & 0xFFu)         | ((xB & 0xFFu) << 16);
                dw.y = 0x43004300u | ((xA >> 8) & 0xFFu)  | (((xB >> 8) & 0xFFu) << 16);
                dw.z = 0x43004300u | ((xA >> 16) & 0xFFu) | (((xB >> 16) & 0xFFu) << 16);
                dw.w = 0x43004300u | (xA >> 24)           | ((xB >> 24) << 16);
                *(uint4*)((char*)Bt + ((n * 128 + krow * 16) ^ ((n & 7) << 4))) = dw;
            }
            __syncthreads();
#pragma unroll
            for (int ks = 0; ks < 2; ++ks) {
                short8v av[2], bv[8];
#pragma unroll
                for (int mf = 0; mf < 2; ++mf) {
                    int m = w * 32 + mf * 16 + lr;
                    av[mf] = *(const short8v*)((char*)Ahi +
                              ((m * 128 + lg * 16 + ks * 64) ^ ((m & 7) << 4)));
                }
#pragma unroll
                for (int nf = 0; nf < 8; ++nf) {
                    int n = nf * 16 + lr;
                    bv[nf] = *(const short8v*)((char*)Bt +
                              ((n * 128 + lg * 16 + ks * 64) ^ ((n & 7) << 4)));
                }
                const bool first = (hf == 0 && ks == 0);
#pragma unroll
                for (int mf = 0; mf < 2; ++mf) {
                    os[mf] = __builtin_amdgcn_mfma_f32_16x16x32_bf16(
                        av[mf], ones, first ? zc : os[mf], 0, 0, 0);
#pragma unroll
                    for (int nf = 0; nf < 8; ++nf)
                        gacc[mf][nf] = __builtin_amdgcn_mfma_f32_16x16x32_bf16(
                            av[mf], bv[nf], first ? zc : gacc[mf][nf], 0, 0, 0);
                }
            }
            __syncthreads();
        }
#pragma unroll
        for (int nf = 0; nf < 8; ++nf) {
            int col = n0 + nf * 16 + lr;
            float sc = SC[(size_t)g * N + col];
            float sz = sc * ((float)QZ[(size_t)g * N + col] + 128.0f);
#pragma unroll
            for (int mf = 0; mf < 2; ++mf)
#pragma unroll
                for (int r = 0; r < 4; ++r)
                    macc[mf][nf][r] += sc * gacc[mf][nf][r] - sz * os[mf][r];
        }
    }
#pragma unroll
    for (int mf = 0; mf < 2; ++mf)
#pragma unroll
        for (int r = 0; r < 4; ++r) {
            int row = m0 + w * 32 + mf * 16 + lg * 4 + r;
#pragma unroll
            for (int nf = 0; nf < 8; ++nf)
                Y[(size_t)row * N + n0 + nf * 16 + lr] = macc[mf][nf][r];
        }
}

// ---------------------------------------------------------------------------
// Causal GQA flash attention, bf16 MFMA, compensated hi/lo QK^T.
// Q/K hi/lo precomputed (roped, Q scaled); K/V staged via global_load_lds
// with pre-swizzled sources (zero staging VALU).
// ---------------------------------------------------------------------------
__global__ __launch_bounds__(256) void attn_mfma_kernel(
    const ushort* __restrict__ Qh, const ushort* __restrict__ Ql,
    const ushort* __restrict__ Kh, const ushort* __restrict__ Kl,
    const ushort* __restrict__ Vt, ushort* __restrict__ AO)
{
    __shared__ ushort KsH[32 * 128];   // 8 KB, swz ^((row&7)<<4)
    __shared__ ushort KsL[32 * 128];
    __shared__ ushort Vs[128 * 32];    // 8 KB, swz ^((dim&3)<<4)
    __shared__ ushort Ps[4][16 * 32];

    const int h  = blockIdx.x;
    const int qb = gridDim.y - 1 - blockIdx.y;
    const int s0 = qb * 64;
    const int t  = threadIdx.x;
    const int w  = t >> 6;
    const int l  = t & 63;
    const int lg = l >> 4;
    const int lr = l & 15;
    const int kvh = h >> 2;
    const int qw = s0 + w * 16;

    short8v qhi[4], qlo[4];
#pragma unroll
    for (int d = 0; d < 4; ++d) {
        size_t off = (size_t)(qw + lr) * (NH * HD) + h * HD + d * 32 + lg * 8;
        qhi[d] = *(const short8v*)&Qh[off];
        qlo[d] = *(const short8v*)&Ql[off];
    }

    f32x4 o[8];
#pragma unroll
    for (int i = 0; i < 8; ++i) o[i] = f32x4{0.f, 0.f, 0.f, 0.f};
    float m[4], lsum[4];
#pragma unroll
    for (int r = 0; r < 4; ++r) { m[r] = -1e30f; lsum[r] = 0.f; }

    const int ntiles = qb * 2 + 2;
    for (int kt = 0; kt < ntiles; ++kt) {
        const int k0 = kt * 32;
        // K hi/lo tiles: 512 slots each (32 rows x 16 chunks)
#pragma unroll
        for (int i = 0; i < 2; ++i) {
            int slot = w * 128 + i * 64 + l;
            int mr = slot >> 4, c = slot & 15;
            size_t goff = (size_t)(k0 + mr) * (NKV * HD) + kvh * HD + ((c ^ (mr & 7)) * 8);
            gl_lds16(Kh + goff, (char*)KsH + (w * 128 + i * 64) * 16);
            gl_lds16(Kl + goff, (char*)KsL + (w * 128 + i * 64) * 16);
        }
        // V^T tile: 512 slots (128 dims x 4 chunks)
#pragma unroll
        for (int i = 0; i < 2; ++i) {
            int slot = w * 128 + i * 64 + l;
            int dim = slot >> 2, c = slot & 3;
            size_t goff = (size_t)(kvh * HD + dim) * S_LEN + k0 + ((c ^ (dim & 3)) * 8);
            gl_lds16(Vt + goff, (char*)Vs + (w * 128 + i * 64) * 16);
        }
        __syncthreads();

        if (k0 <= qw + 15) {
            f32x4 s[2];
            s[0] = f32x4{0.f, 0.f, 0.f, 0.f};
            s[1] = f32x4{0.f, 0.f, 0.f, 0.f};
#pragma unroll
            for (int d = 0; d < 4; ++d) {
#pragma unroll
                for (int nt2 = 0; nt2 < 2; ++nt2) {
                    int row = nt2 * 16 + lr;
                    int off = row * 256 + ((d * 64 + lg * 16) ^ ((row & 7) << 4));
                    short8v kh = *(const short8v*)((char*)KsH + off);
                    short8v kl = *(const short8v*)((char*)KsL + off);
                    s[nt2] = __builtin_amdgcn_mfma_f32_16x16x32_bf16(qhi[d], kh, s[nt2], 0, 0, 0);
                    s[nt2] = __builtin_amdgcn_mfma_f32_16x16x32_bf16(qlo[d], kh, s[nt2], 0, 0, 0);
                    s[nt2] = __builtin_amdgcn_mfma_f32_16x16x32_bf16(qhi[d], kl, s[nt2], 0, 0, 0);
                }
            }
            float p0a[4], p1a[4], resc[4];
#pragma unroll
            for (int r = 0; r < 4; ++r) {
                int qrow = qw + lg * 4 + r;
                float s0v = (k0 + lr      <= qrow) ? s[0][r] : -1e30f;
                float s1v = (k0 + 16 + lr <= qrow) ? s[1][r] : -1e30f;
                float mx = fmaxf(s0v, s1v);
                mx = fmaxf(mx, __shfl_xor(mx, 1));
                mx = fmaxf(mx, __shfl_xor(mx, 2));
                mx = fmaxf(mx, __shfl_xor(mx, 4));
                mx = fmaxf(mx, __shfl_xor(mx, 8));
                float mnew = fmaxf(m[r], mx);
                resc[r] = __expf(m[r] - mnew);
                m[r] = mnew;
                float p0 = __expf(s0v - mnew);
                float p1 = __expf(s1v - mnew);
                p0a[r] = p0; p1a[r] = p1;
                float ps = p0 + p1;
                ps += __shfl_xor(ps, 1);
                ps += __shfl_xor(ps, 2);
                ps += __shfl_xor(ps, 4);
                ps += __shfl_xor(ps, 8);
                lsum[r] = lsum[r] * resc[r] + ps;
            }
#pragma unroll
            for (int dt = 0; dt < 8; ++dt)
#pragma unroll
                for (int r = 0; r < 4; ++r) o[dt][r] *= resc[r];
            ushort* pw = Ps[w];
#pragma unroll
            for (int r = 0; r < 4; ++r) {
                int row = lg * 4 + r;
                *(ushort*)((char*)pw + row * 64 + (((lr)      * 2) ^ ((row & 3) << 4))) = f2bf(p0a[r]);
                *(ushort*)((char*)pw + row * 64 + (((lr + 16) * 2) ^ ((row & 3) << 4))) = f2bf(p1a[r]);
            }
            asm volatile("s_waitcnt lgkmcnt(0)" ::: "memory");
            short8v pf = *(const short8v*)((char*)pw + lr * 64 + ((lg * 16) ^ ((lr & 3) << 4)));
#pragma unroll
            for (int dt = 0; dt < 8; ++dt) {
                int dim = dt * 16 + lr;
                short8v vf = *(const short8v*)((char*)Vs + dim * 64 + ((lg * 16) ^ ((dim & 3) << 4)));
                o[dt] = __builtin_amdgcn_mfma_f32_16x16x32_bf16(pf, vf, o[dt], 0, 0, 0);
            }
        }
        __syncthreads();
    }

#pragma unroll
    for (int r = 0; r < 4; ++r) {
        float inv = 1.f / lsum[r];
        int qrow = qw + lg * 4 + r;
        ushort* dst = &AO[(size_t)qrow * (NH * HD) + h * HD];
#pragma unroll
        for (int dt = 0; dt < 8; ++dt) dst[dt * 16 + lr] = f2bf(o[dt][r] * inv);
    }
}

// ---------------------------------------------------------------------------
extern "C" void kernel_launch(void* const* d_in, const int* in_sizes, int n_in,
                              void* d_out, int out_size, void* d_ws, size_t ws_size,
                              hipStream_t stream)
{
    const float* x    = (const float*)d_in[0];
    const float* cosb = (const float*)d_in[1];
    const float* sinb = (const float*)d_in[2];
    const float* q_sc = (const float*)d_in[3];
    const float* q_b  = (const float*)d_in[4];
    const float* k_sc = (const float*)d_in[5];
    const float* k_b  = (const float*)d_in[6];
    const float* v_sc = (const float*)d_in[7];
    const float* v_b  = (const float*)d_in[8];
    const float* o_sc = (const float*)d_in[9];
    const int* q_qw   = (const int*)d_in[10];
    const int* q_qz   = (const int*)d_in[11];
    const int* k_qw   = (const int*)d_in[12];
    const int* k_qz   = (const int*)d_in[13];
    const int* v_qw   = (const int*)d_in[14];
    const int* v_qz   = (const int*)d_in[15];
    const int* o_qw   = (const int*)d_in[16];
    const int* o_qz   = (const int*)d_in[17];
    float* out = (float*)d_out;

    // ws layout (bytes):
    //   0        : Xhi 10.0MB   [reused as AObf 8MB after QKV GEMM]
    //   10.5MB   : Xlo 10.0MB
    //   21MB     : Qhi 16MB | 37MB: Qlo 16MB
    //   53MB     : Khi 4MB  | 57MB: Klo 4MB | 61MB: VbfT 4MB   (end 65MB)
    char* ws = (char*)d_ws;
    ushort* Xhi  = (ushort*)ws;
    ushort* AObf = (ushort*)ws;                                    // alias (after QKV)
    ushort* Xlo  = (ushort*)(ws + (size_t)10 * 1024 * 1024 + 512 * 1024);
    ushort* Qhi  = (ushort*)(ws + (size_t)21 * 1024 * 1024);
    ushort* Qlo  = (ushort*)(ws + (size_t)37 * 1024 * 1024);
    ushort* Khi  = (ushort*)(ws + (size_t)53 * 1024 * 1024);
    ushort* Klo  = (ushort*)(ws + (size_t)57 * 1024 * 1024);
    ushort* VbfT = (ushort*)(ws + (size_t)61 * 1024 * 1024);

    xsplit_kernel<<<S_LEN * HIDDEN / 1024, 256, 0, stream>>>(x, Xhi, Xlo);

    qkv_mfma_kernel<<<dim3(48, 16), 256, 0, stream>>>(
        Xhi, Xlo,
        q_qw, q_sc, q_qz, q_b,
        k_qw, k_sc, k_qz, k_b,
        v_qw, v_sc, v_qz, v_b,
        cosb, sinb, Qhi, Qlo, Khi, Klo, VbfT);

    attn_mfma_kernel<<<dim3(NH, S_LEN / 64), 256, 0, stream>>>(
        Qhi, Qlo, Khi, Klo, VbfT, AObf);

    oproj_mfma_kernel<<<dim3(HIDDEN / 128, S_LEN / 128), 256, 0, stream>>>(
        AObf, o_qw, o_sc, o_qz, out);
}

// Round 6
// 449.877 us; speedup vs baseline: 2.0285x; 2.0285x over previous
//
#include <hip/hip_runtime.h>
#include <hip/hip_bf16.h>
#include <cstdint>

#define S_LEN 2048
#define HIDDEN 2560
#define NH 32
#define NKV 8
#define HD 128
#define GS 128

typedef __attribute__((ext_vector_type(8))) short short8v;  // 8 x bf16 frag
typedef __attribute__((ext_vector_type(4))) float f32x4;
typedef unsigned int uint;
typedef unsigned short ushort;

__device__ inline ushort f2bf(float f) {
    uint u = __builtin_bit_cast(uint, f);
    u += 0x7fffu + ((u >> 16) & 1u);   // RNE
    return (ushort)(u >> 16);
}
__device__ inline float bf2f(ushort u) {
    return __builtin_bit_cast(float, (uint)u << 16);
}
__device__ inline uint pk2(ushort a, ushort b) { return (uint)a | ((uint)b << 16); }

// async global->LDS, 16B per lane; lds base must be wave-uniform
__device__ __attribute__((always_inline)) inline void gl_lds16(const void* g, void* l) {
    __builtin_amdgcn_global_load_lds(
        (const __attribute__((address_space(1))) unsigned int*)g,
        (__attribute__((address_space(3))) unsigned int*)l, 16, 0, 0);
}

// ---------------------------------------------------------------------------
// X -> hi/lo bf16 split + per-group (128) rowsums RSx[row][20].
// One block per row (2560 els), 320 threads x 8 els.
// ---------------------------------------------------------------------------
__global__ __launch_bounds__(320) void xsplit_rs_kernel(
    const float* __restrict__ X, ushort* __restrict__ Xhi,
    ushort* __restrict__ Xlo, float* __restrict__ RSx)
{
    const int row = blockIdx.x;
    const int t   = threadIdx.x;
    const size_t base = (size_t)row * HIDDEN + t * 8;
    float4 a = *(const float4*)&X[base];
    float4 b = *(const float4*)&X[base + 4];
    float xv[8] = {a.x, a.y, a.z, a.w, b.x, b.y, b.z, b.w};
    ushort hv[8], lv[8];
    float sum = 0.f;
#pragma unroll
    for (int j = 0; j < 8; ++j) {
        hv[j] = f2bf(xv[j]);
        lv[j] = f2bf(xv[j] - bf2f(hv[j]));
        sum += xv[j];
    }
    uint4 hw = {pk2(hv[0], hv[1]), pk2(hv[2], hv[3]), pk2(hv[4], hv[5]), pk2(hv[6], hv[7])};
    uint4 lw = {pk2(lv[0], lv[1]), pk2(lv[2], lv[3]), pk2(lv[4], lv[5]), pk2(lv[6], lv[7])};
    *(uint4*)&Xhi[base] = hw;
    *(uint4*)&Xlo[base] = lw;
    sum += __shfl_xor(sum, 1);
    sum += __shfl_xor(sum, 2);
    sum += __shfl_xor(sum, 4);
    sum += __shfl_xor(sum, 8);
    if ((t & 15) == 0) RSx[(size_t)row * 20 + (t >> 4)] = sum;
}

// ---------------------------------------------------------------------------
// AO (bf16, exact) per-group rowsums RSa[row][32]. 512 thr x 8 els (K=4096).
// ---------------------------------------------------------------------------
__global__ __launch_bounds__(512) void rs_ao_kernel(
    const ushort* __restrict__ AO, float* __restrict__ RSa)
{
    const int row = blockIdx.x;
    const int t   = threadIdx.x;
    uint4 v = *(const uint4*)&AO[(size_t)row * (NH * HD) + t * 8];
    const uint* pw = (const uint*)&v;
    float sum = 0.f;
#pragma unroll
    for (int j = 0; j < 4; ++j) {
        sum += bf2f((ushort)(pw[j] & 0xffff)) + bf2f((ushort)(pw[j] >> 16));
    }
    sum += __shfl_xor(sum, 1);
    sum += __shfl_xor(sum, 2);
    sum += __shfl_xor(sum, 4);
    sum += __shfl_xor(sum, 8);
    if ((t & 15) == 0) RSa[(size_t)row * 32 + (t >> 4)] = sum;
}

// ===========================================================================
// Fused Q/K/V AWQ-int4 MFMA GEMM, 2-phase double-buffered pipeline.
// B = (nib+128) exact bf16 (0x4300|n); y = sc*gacc - sc*(z+128)*RSx + bias.
// 512 thr / 8 waves (2x4), wave tile 64x32. LDS: 2x(Ahi+Alo+Bt) = 96 KB.
// Epilogue: RoPE via 64KB LDS exchange (Q/K -> hi/lo), V -> bf16 [N][M].
// ===========================================================================
__global__ __launch_bounds__(512) void qkv2_kernel(
    const ushort* __restrict__ Xhi, const ushort* __restrict__ Xlo,
    const float* __restrict__ RSx,
    const int* __restrict__ q_qw, const float* __restrict__ q_sc,
    const int* __restrict__ q_qz, const float* __restrict__ q_b,
    const int* __restrict__ k_qw, const float* __restrict__ k_sc,
    const int* __restrict__ k_qz, const float* __restrict__ k_b,
    const int* __restrict__ v_qw, const float* __restrict__ v_sc,
    const int* __restrict__ v_qz, const float* __restrict__ v_b,
    const float* __restrict__ cosb, const float* __restrict__ sinb,
    ushort* __restrict__ Qhi, ushort* __restrict__ Qlo,
    ushort* __restrict__ Khi, ushort* __restrict__ Klo,
    ushort* __restrict__ VbfT)
{
    __shared__ __align__(16) char LDSB[98304];
    ushort* Ahi0 = (ushort*)(LDSB);
    ushort* Ahi1 = (ushort*)(LDSB + 16384);
    ushort* Alo0 = (ushort*)(LDSB + 32768);
    ushort* Alo1 = (ushort*)(LDSB + 49152);
    ushort* Bt0  = (ushort*)(LDSB + 65536);
    ushort* Bt1  = (ushort*)(LDSB + 81920);
    float*  EP   = (float*)(LDSB);          // 64 KB epilogue scratch [128][128]

    const int t  = threadIdx.x;
    const int w  = t >> 6;
    const int l  = t & 63;
    const int lg = l >> 4;
    const int lr = l & 15;
    const int wr = w >> 2;       // 0..1 : M half
    const int wc = w & 3;        // 0..3 : N quarter
    const int K  = HIDDEN;

    // XCD-bijective swizzle (768 = 8 * 96)
    const int bid = blockIdx.x;
    const int swz = (bid & 7) * 96 + (bid >> 3);
    const int bx  = swz % 48;
    const int m0  = (swz / 48) * 128;

    int region, nbase, Nw;
    const int* QW; const float* SC; const int* QZ; const float* BI;
    if (bx < 32)      { region = 0; nbase = bx * 128;        Nw = NH * HD;
                        QW = q_qw; SC = q_sc; QZ = q_qz; BI = q_b; }
    else if (bx < 40) { region = 1; nbase = (bx - 32) * 128; Nw = NKV * HD;
                        QW = k_qw; SC = k_sc; QZ = k_qz; BI = k_b; }
    else              { region = 2; nbase = (bx - 40) * 128; Nw = NKV * HD;
                        QW = v_qw; SC = v_sc; QZ = v_qz; BI = v_b; }

    // A-chunk addressing (per thread: 2 chunks hi + 2 lo)
    const int am0 = t >> 3, ac0 = t & 7;
    const size_t aoff0 = (size_t)(m0 + am0) * K + (size_t)((ac0 ^ (am0 & 7)) * 8);
    const size_t aoff1 = aoff0 + (size_t)64 * K;     // (am0+64)&7 == am0&7
    const int ldsA0 = w * 1024;                      // bytes, wave-uniform
    const int ldsA1 = 8192 + w * 1024;
    // B addressing
    const int bkr = t >> 7, bn = t & 127;
    const int bwoff0 = (bn * 128 + bkr * 16) ^ ((bn & 7) << 4);
    const int bwoff1 = (bn * 128 + (bkr + 4) * 16) ^ ((bn & 7) << 4);
    const int xorA = (lr & 7) << 4;

    f32x4 macc[4][2];
#pragma unroll
    for (int mf = 0; mf < 4; ++mf)
#pragma unroll
        for (int nf = 0; nf < 2; ++nf) macc[mf][nf] = f32x4{0.f, 0.f, 0.f, 0.f};
    f32x4 gacc[4][2];
    const f32x4 zc = f32x4{0.f, 0.f, 0.f, 0.f};
    uint qr0, qr1;

#define QKV_QW(tile) { int g8 = (tile) * 8; \
    qr0 = (uint)QW[(size_t)(g8 + bkr) * Nw + nbase + bn]; \
    qr1 = (uint)QW[(size_t)(g8 + 4 + bkr) * Nw + nbase + bn]; }

#define QKV_STAGE_A(AH, AL, k0) { \
    gl_lds16(Xhi + (k0) + aoff0, (char*)(AH) + ldsA0); \
    gl_lds16(Xhi + (k0) + aoff1, (char*)(AH) + ldsA1); \
    gl_lds16(Xlo + (k0) + aoff0, (char*)(AL) + ldsA0); \
    gl_lds16(Xlo + (k0) + aoff1, (char*)(AL) + ldsA1); }

#define QKV_BWRITE(BT) { \
    uint xA = qr0 & 0x0F0F0F0Fu, xB = (qr0 >> 4) & 0x0F0F0F0Fu; \
    uint4 dw; \
    dw.x = 0x43004300u | (xA & 0xFFu)         | ((xB & 0xFFu) << 16); \
    dw.y = 0x43004300u | ((xA >> 8) & 0xFFu)  | (((xB >> 8) & 0xFFu) << 16); \
    dw.z = 0x43004300u | ((xA >> 16) & 0xFFu) | (((xB >> 16) & 0xFFu) << 16); \
    dw.w = 0x43004300u | (xA >> 24)           | ((xB >> 24) << 16); \
    *(uint4*)((char*)(BT) + bwoff0) = dw; \
    xA = qr1 & 0x0F0F0F0Fu; xB = (qr1 >> 4) & 0x0F0F0F0Fu; \
    dw.x = 0x43004300u | (xA & 0xFFu)         | ((xB & 0xFFu) << 16); \
    dw.y = 0x43004300u | ((xA >> 8) & 0xFFu)  | (((xB >> 8) & 0xFFu) << 16); \
    dw.z = 0x43004300u | ((xA >> 16) & 0xFFu) | (((xB >> 16) & 0xFFu) << 16); \
    dw.w = 0x43004300u | (xA >> 24)           | ((xB >> 24) << 16); \
    *(uint4*)((char*)(BT) + bwoff1) = dw; }

#define QKV_COMPUTE(AH, AL, BT, INIT) { \
    _Pragma("unroll") \
    for (int ks = 0; ks < 2; ++ks) { \
        short8v av[4], avl[4], bv[2]; \
        _Pragma("unroll") \
        for (int mf = 0; mf < 4; ++mf) { \
            int off = (((wr * 64 + mf * 16 + lr) * 128) + lg * 16 + ks * 64) ^ xorA; \
            av[mf]  = *(const short8v*)((const char*)(AH) + off); \
            avl[mf] = *(const short8v*)((const char*)(AL) + off); \
        } \
        _Pragma("unroll") \
        for (int nf = 0; nf < 2; ++nf) { \
            int off = (((wc * 32 + nf * 16 + lr) * 128) + lg * 16 + ks * 64) ^ xorA; \
            bv[nf] = *(const short8v*)((const char*)(BT) + off); \
        } \
        _Pragma("unroll") \
        for (int mf = 0; mf < 4; ++mf) \
            _Pragma("unroll") \
            for (int nf = 0; nf < 2; ++nf) { \
                f32x4 c = ((INIT) && ks == 0) ? zc : gacc[mf][nf]; \
                c = __builtin_amdgcn_mfma_f32_16x16x32_bf16(av[mf], bv[nf], c, 0, 0, 0); \
                gacc[mf][nf] = __builtin_amdgcn_mfma_f32_16x16x32_bf16(avl[mf], bv[nf], c, 0, 0, 0); \
            } \
    } }

#define QKV_RESCALE(g) { \
    float rsv[4][4]; \
    _Pragma("unroll") \
    for (int mf = 0; mf < 4; ++mf) \
        _Pragma("unroll") \
        for (int r = 0; r < 4; ++r) \
            rsv[mf][r] = RSx[(size_t)(m0 + wr * 64 + mf * 16 + lg * 4 + r) * 20 + (g)]; \
    _Pragma("unroll") \
    for (int nf = 0; nf < 2; ++nf) { \
        int col = nbase + wc * 32 + nf * 16 + lr; \
        float sc = SC[(size_t)(g) * Nw + col]; \
        float sz = sc * ((float)QZ[(size_t)(g) * Nw + col] + 128.0f); \
        _Pragma("unroll") \
        for (int mf = 0; mf < 4; ++mf) \
            _Pragma("unroll") \
            for (int r = 0; r < 4; ++r) \
                macc[mf][nf][r] += sc * gacc[mf][nf][r] - sz * rsv[mf][r]; \
    } }

    // prologue: stage tile 0 into buf0
    QKV_QW(0);
    QKV_STAGE_A(Ahi0, Alo0, 0);
    QKV_BWRITE(Bt0);
    __syncthreads();

    for (int g = 0; g < 20; ++g) {
        const int t1 = 2 * g + 1;
        QKV_QW(t1);
        QKV_STAGE_A(Ahi1, Alo1, t1 * 64);
        QKV_COMPUTE(Ahi0, Alo0, Bt0, true);
        QKV_BWRITE(Bt1);
        __syncthreads();
        if (g < 19) {
            const int t2 = 2 * g + 2;
            QKV_QW(t2);
            QKV_STAGE_A(Ahi0, Alo0, t2 * 64);
        }
        QKV_COMPUTE(Ahi1, Alo1, Bt1, false);
        if (g < 19) QKV_BWRITE(Bt0);
        QKV_RESCALE(g);
        __syncthreads();
    }

    // ---- epilogue: +bias -> EP[128][128] -> exchange ----
#pragma unroll
    for (int nf = 0; nf < 2; ++nf) {
        float bv = BI[nbase + wc * 32 + nf * 16 + lr];
#pragma unroll
        for (int mf = 0; mf < 4; ++mf)
#pragma unroll
            for (int r = 0; r < 4; ++r)
                EP[(wr * 64 + mf * 16 + lg * 4 + r) * 128 + wc * 32 + nf * 16 + lr] =
                    macc[mf][nf][r] + bv;
    }
    __syncthreads();

    if (region == 2) {
        // V: transposed bf16 store, coalesced along rows
        const int col = t >> 2, rseg = (t & 3) * 32;
        ushort ob[32];
#pragma unroll
        for (int j = 0; j < 32; ++j) ob[j] = f2bf(EP[(rseg + j) * 128 + col]);
        ushort* dst = &VbfT[(size_t)(nbase + col) * S_LEN + m0 + rseg];
#pragma unroll
        for (int j = 0; j < 4; ++j) *(uint4*)(dst + j * 8) = ((uint4*)ob)[j];
    } else {
        // Q/K: RoPE (fp32) -> hi/lo bf16
        ushort* OH = (region == 0) ? Qhi : Khi;
        ushort* OL = (region == 0) ? Qlo : Klo;
        const int No = (region == 0) ? NH * HD : NKV * HD;
        const float osc = (region == 0) ? 0.08838834764831845f : 1.0f;
        const int row = t >> 2, cseg = (t & 3) * 32;
        const int grow = m0 + row;
        ushort hb[32], lb[32];
#pragma unroll
        for (int j = 0; j < 32; ++j) {
            int c2 = cseg + j;
            float a = EP[row * 128 + c2];
            float p = EP[row * 128 + (c2 ^ 64)];
            float cs = cosb[(size_t)grow * HD + c2];
            float sn = sinb[(size_t)grow * HD + c2];
            float o = (c2 < 64) ? (a * cs - p * sn) : (a * cs + p * sn);
            o *= osc;
            hb[j] = f2bf(o);
            lb[j] = f2bf(o - bf2f(hb[j]));
        }
        ushort* dh = &OH[(size_t)grow * No + nbase + cseg];
        ushort* dl = &OL[(size_t)grow * No + nbase + cseg];
#pragma unroll
        for (int j = 0; j < 4; ++j) {
            *(uint4*)(dh + j * 8) = ((uint4*)hb)[j];
            *(uint4*)(dl + j * 8) = ((uint4*)lb)[j];
        }
    }
#undef QKV_QW
#undef QKV_STAGE_A
#undef QKV_BWRITE
#undef QKV_COMPUTE
#undef QKV_RESCALE
}

// ===========================================================================
// O-projection, same 2-phase pipeline; X = AO bf16 exact (hi only).
// K=4096 (32 groups), N=2560, f32 out. LDS: 2x(Ahi+Bt) = 64 KB.
// ===========================================================================
__global__ __launch_bounds__(512) void oproj2_kernel(
    const ushort* __restrict__ Xb, const float* __restrict__ RSa,
    const int* __restrict__ QW, const float* __restrict__ SC,
    const int* __restrict__ QZ, float* __restrict__ Y)
{
    __shared__ __align__(16) char LDSB[65536];
    ushort* Ahi0 = (ushort*)(LDSB);
    ushort* Ahi1 = (ushort*)(LDSB + 16384);
    ushort* Bt0  = (ushort*)(LDSB + 32768);
    ushort* Bt1  = (ushort*)(LDSB + 49152);

    const int t  = threadIdx.x;
    const int w  = t >> 6;
    const int l  = t & 63;
    const int lg = l >> 4;
    const int lr = l & 15;
    const int wr = w >> 2;
    const int wc = w & 3;
    const int K  = NH * HD;      // 4096
    const int N  = HIDDEN;       // 2560

    const int bid = blockIdx.x;
    const int swz = (bid & 7) * 40 + (bid >> 3);   // 320 = 8*40
    const int n0  = (swz % 20) * 128;
    const int m0  = (swz / 20) * 128;

    const int am0 = t >> 3, ac0 = t & 7;
    const size_t aoff0 = (size_t)(m0 + am0) * K + (size_t)((ac0 ^ (am0 & 7)) * 8);
    const size_t aoff1 = aoff0 + (size_t)64 * K;
    const int ldsA0 = w * 1024;
    const int ldsA1 = 8192 + w * 1024;
    const int bkr = t >> 7, bn = t & 127;
    const int bwoff0 = (bn * 128 + bkr * 16) ^ ((bn & 7) << 4);
    const int bwoff1 = (bn * 128 + (bkr + 4) * 16) ^ ((bn & 7) << 4);
    const int xorA = (lr & 7) << 4;

    f32x4 macc[4][2];
#pragma unroll
    for (int mf = 0; mf < 4; ++mf)
#pragma unroll
        for (int nf = 0; nf < 2; ++nf) macc[mf][nf] = f32x4{0.f, 0.f, 0.f, 0.f};
    f32x4 gacc[4][2];
    const f32x4 zc = f32x4{0.f, 0.f, 0.f, 0.f};
    uint qr0, qr1;

#define OP_QW(tile) { int g8 = (tile) * 8; \
    qr0 = (uint)QW[(size_t)(g8 + bkr) * N + n0 + bn]; \
    qr1 = (uint)QW[(size_t)(g8 + 4 + bkr) * N + n0 + bn]; }

#define OP_STAGE_A(AH, k0) { \
    gl_lds16(Xb + (k0) + aoff0, (char*)(AH) + ldsA0); \
    gl_lds16(Xb + (k0) + aoff1, (char*)(AH) + ldsA1); }

#define OP_BWRITE(BT) { \
    uint xA = qr0 & 0x0F0F0F0Fu, xB = (qr0 >> 4) & 0x0F0F0F0Fu; \
    uint4 dw; \
    dw.x = 0x43004300u | (xA & 0xFFu)         | ((xB & 0xFFu) << 16); \
    dw.y = 0x43004300u | ((xA >> 8) & 0xFFu)  | (((xB >> 8) & 0xFFu) << 16); \
    dw.z = 0x43004300u | ((xA >> 16) & 0xFFu) | (((xB >> 16) & 0xFFu) << 16); \
    dw.w = 0x43004300u | (xA >> 24)           | ((xB >> 24) << 16); \
    *(uint4*)((char*)(BT) + bwoff0) = dw; \
    xA = qr1 & 0x0F0F0F0Fu; xB = (qr1 >> 4) & 0x0F0F0F0Fu; \
    dw.x = 0x43004300u | (xA & 0xFFu)         | ((xB & 0xFFu) << 16); \
    dw.y = 0x43004300u | ((xA >> 8) & 0xFFu)  | (((xB >> 8) & 0xFFu) << 16); \
    dw.z = 0x43004300u | ((xA >> 16) & 0xFFu) | (((xB >> 16) & 0xFFu) << 16); \
    dw.w = 0x43004300u | (xA >> 24)           | ((xB >> 24) << 16); \
    *(uint4*)((char*)(BT) + bwoff1) = dw; }

#define OP_COMPUTE(AH, BT, INIT) { \
    _Pragma("unroll") \
    for (int ks = 0; ks < 2; ++ks) { \
        short8v av[4], bv[2]; \
        _Pragma("unroll") \
        for (int mf = 0; mf < 4; ++mf) { \
            int off = (((wr * 64 + mf * 16 + lr) * 128) + lg * 16 + ks * 64) ^ xorA; \
            av[mf] = *(const short8v*)((const char*)(AH) + off); \
        } \
        _Pragma("unroll") \
        for (int nf = 0; nf < 2; ++nf) { \
            int off = (((wc * 32 + nf * 16 + lr) * 128) + lg * 16 + ks * 64) ^ xorA; \
            bv[nf] = *(const short8v*)((const char*)(BT) + off); \
        } \
        _Pragma("unroll") \
        for (int mf = 0; mf < 4; ++mf) \
            _Pragma("unroll") \
            for (int nf = 0; nf < 2; ++nf) { \
                f32x4 c = ((INIT) && ks == 0) ? zc : gacc[mf][nf]; \
                gacc[mf][nf] = __builtin_amdgcn_mfma_f32_16x16x32_bf16(av[mf], bv[nf], c, 0, 0, 0); \
            } \
    } }

#define OP_RESCALE(g) { \
    float rsv[4][4]; \
    _Pragma("unroll") \
    for (int mf = 0; mf < 4; ++mf) \
        _Pragma("unroll") \
        for (int r = 0; r < 4; ++r) \
            rsv[mf][r] = RSa[(size_t)(m0 + wr * 64 + mf * 16 + lg * 4 + r) * 32 + (g)]; \
    _Pragma("unroll") \
    for (int nf = 0; nf < 2; ++nf) { \
        int col = n0 + wc * 32 + nf * 16 + lr; \
        float sc = SC[(size_t)(g) * N + col]; \
        float sz = sc * ((float)QZ[(size_t)(g) * N + col] + 128.0f); \
        _Pragma("unroll") \
        for (int mf = 0; mf < 4; ++mf) \
            _Pragma("unroll") \
            for (int r = 0; r < 4; ++r) \
                macc[mf][nf][r] += sc * gacc[mf][nf][r] - sz * rsv[mf][r]; \
    } }

    OP_QW(0);
    OP_STAGE_A(Ahi0, 0);
    OP_BWRITE(Bt0);
    __syncthreads();

    for (int g = 0; g < 32; ++g) {
        const int t1 = 2 * g + 1;
        OP_QW(t1);
        OP_STAGE_A(Ahi1, t1 * 64);
        OP_COMPUTE(Ahi0, Bt0, true);
        OP_BWRITE(Bt1);
        __syncthreads();
        if (g < 31) {
            const int t2 = 2 * g + 2;
            OP_QW(t2);
            OP_STAGE_A(Ahi0, t2 * 64);
        }
        OP_COMPUTE(Ahi1, Bt1, false);
        if (g < 31) OP_BWRITE(Bt0);
        OP_RESCALE(g);
        __syncthreads();
    }

#pragma unroll
    for (int mf = 0; mf < 4; ++mf)
#pragma unroll
        for (int r = 0; r < 4; ++r) {
            int row = m0 + wr * 64 + mf * 16 + lg * 4 + r;
#pragma unroll
            for (int nf = 0; nf < 2; ++nf)
                Y[(size_t)row * N + n0 + wc * 32 + nf * 16 + lr] = macc[mf][nf][r];
        }
#undef OP_QW
#undef OP_STAGE_A
#undef OP_BWRITE
#undef OP_COMPUTE
#undef OP_RESCALE
}

// ---------------------------------------------------------------------------
// Causal GQA flash attention, bf16 MFMA, compensated hi/lo QK^T.
// (unchanged from round 5 — verified)
// ---------------------------------------------------------------------------
__global__ __launch_bounds__(256) void attn_mfma_kernel(
    const ushort* __restrict__ Qh, const ushort* __restrict__ Ql,
    const ushort* __restrict__ Kh, const ushort* __restrict__ Kl,
    const ushort* __restrict__ Vt, ushort* __restrict__ AO)
{
    __shared__ ushort KsH[32 * 128];
    __shared__ ushort KsL[32 * 128];
    __shared__ ushort Vs[128 * 32];
    __shared__ ushort Ps[4][16 * 32];

    const int h  = blockIdx.x;
    const int qb = gridDim.y - 1 - blockIdx.y;
    const int s0 = qb * 64;
    const int t  = threadIdx.x;
    const int w  = t >> 6;
    const int l  = t & 63;
    const int lg = l >> 4;
    const int lr = l & 15;
    const int kvh = h >> 2;
    const int qw = s0 + w * 16;

    short8v qhi[4], qlo[4];
#pragma unroll
    for (int d = 0; d < 4; ++d) {
        size_t off = (size_t)(qw + lr) * (NH * HD) + h * HD + d * 32 + lg * 8;
        qhi[d] = *(const short8v*)&Qh[off];
        qlo[d] = *(const short8v*)&Ql[off];
    }

    f32x4 o[8];
#pragma unroll
    for (int i = 0; i < 8; ++i) o[i] = f32x4{0.f, 0.f, 0.f, 0.f};
    float m[4], lsum[4];
#pragma unroll
    for (int r = 0; r < 4; ++r) { m[r] = -1e30f; lsum[r] = 0.f; }

    const int ntiles = qb * 2 + 2;
    for (int kt = 0; kt < ntiles; ++kt) {
        const int k0 = kt * 32;
#pragma unroll
        for (int i = 0; i < 2; ++i) {
            int slot = w * 128 + i * 64 + l;
            int mr = slot >> 4, c = slot & 15;
            size_t goff = (size_t)(k0 + mr) * (NKV * HD) + kvh * HD + ((c ^ (mr & 7)) * 8);
            gl_lds16(Kh + goff, (char*)KsH + (w * 128 + i * 64) * 16);
            gl_lds16(Kl + goff, (char*)KsL + (w * 128 + i * 64) * 16);
        }
#pragma unroll
        for (int i = 0; i < 2; ++i) {
            int slot = w * 128 + i * 64 + l;
            int dim = slot >> 2, c = slot & 3;
            size_t goff = (size_t)(kvh * HD + dim) * S_LEN + k0 + ((c ^ (dim & 3)) * 8);
            gl_lds16(Vt + goff, (char*)Vs + (w * 128 + i * 64) * 16);
        }
        __syncthreads();

        if (k0 <= qw + 15) {
            f32x4 s[2];
            s[0] = f32x4{0.f, 0.f, 0.f, 0.f};
            s[1] = f32x4{0.f, 0.f, 0.f, 0.f};
#pragma unroll
            for (int d = 0; d < 4; ++d) {
#pragma unroll
                for (int nt2 = 0; nt2 < 2; ++nt2) {
                    int row = nt2 * 16 + lr;
                    int off = row * 256 + ((d * 64 + lg * 16) ^ ((row & 7) << 4));
                    short8v kh = *(const short8v*)((char*)KsH + off);
                    short8v kl = *(const short8v*)((char*)KsL + off);
                    s[nt2] = __builtin_amdgcn_mfma_f32_16x16x32_bf16(qhi[d], kh, s[nt2], 0, 0, 0);
                    s[nt2] = __builtin_amdgcn_mfma_f32_16x16x32_bf16(qlo[d], kh, s[nt2], 0, 0, 0);
                    s[nt2] = __builtin_amdgcn_mfma_f32_16x16x32_bf16(qhi[d], kl, s[nt2], 0, 0, 0);
                }
            }
            float p0a[4], p1a[4], resc[4];
#pragma unroll
            for (int r = 0; r < 4; ++r) {
                int qrow = qw + lg * 4 + r;
                float s0v = (k0 + lr      <= qrow) ? s[0][r] : -1e30f;
                float s1v = (k0 + 16 + lr <= qrow) ? s[1][r] : -1e30f;
                float mx = fmaxf(s0v, s1v);
                mx = fmaxf(mx, __shfl_xor(mx, 1));
                mx = fmaxf(mx, __shfl_xor(mx, 2));
                mx = fmaxf(mx, __shfl_xor(mx, 4));
                mx = fmaxf(mx, __shfl_xor(mx, 8));
                float mnew = fmaxf(m[r], mx);
                resc[r] = __expf(m[r] - mnew);
                m[r] = mnew;
                float p0 = __expf(s0v - mnew);
                float p1 = __expf(s1v - mnew);
                p0a[r] = p0; p1a[r] = p1;
                float ps = p0 + p1;
                ps += __shfl_xor(ps, 1);
                ps += __shfl_xor(ps, 2);
                ps += __shfl_xor(ps, 4);
                ps += __shfl_xor(ps, 8);
                lsum[r] = lsum[r] * resc[r] + ps;
            }
#pragma unroll
            for (int dt = 0; dt < 8; ++dt)
#pragma unroll
                for (int r = 0; r < 4; ++r) o[dt][r] *= resc[r];
            ushort* pw = Ps[w];
#pragma unroll
            for (int r = 0; r < 4; ++r) {
                int row = lg * 4 + r;
                *(ushort*)((char*)pw + row * 64 + (((lr)      * 2) ^ ((row & 3) << 4))) = f2bf(p0a[r]);
                *(ushort*)((char*)pw + row * 64 + (((lr + 16) * 2) ^ ((row & 3) << 4))) = f2bf(p1a[r]);
            }
            asm volatile("s_waitcnt lgkmcnt(0)" ::: "memory");
            short8v pf = *(const short8v*)((char*)pw + lr * 64 + ((lg * 16) ^ ((lr & 3) << 4)));
#pragma unroll
            for (int dt = 0; dt < 8; ++dt) {
                int dim = dt * 16 + lr;
                short8v vf = *(const short8v*)((char*)Vs + dim * 64 + ((lg * 16) ^ ((dim & 3) << 4)));
                o[dt] = __builtin_amdgcn_mfma_f32_16x16x32_bf16(pf, vf, o[dt], 0, 0, 0);
            }
        }
        __syncthreads();
    }

#pragma unroll
    for (int r = 0; r < 4; ++r) {
        float inv = 1.f / lsum[r];
        int qrow = qw + lg * 4 + r;
        ushort* dst = &AO[(size_t)qrow * (NH * HD) + h * HD];
#pragma unroll
        for (int dt = 0; dt < 8; ++dt) dst[dt * 16 + lr] = f2bf(o[dt][r] * inv);
    }
}

// ---------------------------------------------------------------------------
extern "C" void kernel_launch(void* const* d_in, const int* in_sizes, int n_in,
                              void* d_out, int out_size, void* d_ws, size_t ws_size,
                              hipStream_t stream)
{
    const float* x    = (const float*)d_in[0];
    const float* cosb = (const float*)d_in[1];
    const float* sinb = (const float*)d_in[2];
    const float* q_sc = (const float*)d_in[3];
    const float* q_b  = (const float*)d_in[4];
    const float* k_sc = (const float*)d_in[5];
    const float* k_b  = (const float*)d_in[6];
    const float* v_sc = (const float*)d_in[7];
    const float* v_b  = (const float*)d_in[8];
    const float* o_sc = (const float*)d_in[9];
    const int* q_qw   = (const int*)d_in[10];
    const int* q_qz   = (const int*)d_in[11];
    const int* k_qw   = (const int*)d_in[12];
    const int* k_qz   = (const int*)d_in[13];
    const int* v_qw   = (const int*)d_in[14];
    const int* v_qz   = (const int*)d_in[15];
    const int* o_qw   = (const int*)d_in[16];
    const int* o_qz   = (const int*)d_in[17];
    float* out = (float*)d_out;

    // ws layout (MB):
    //   0..10   Xhi        [aliased by AObf 0..16 after QKV is done]
    //   10.5..  Xlo (10)
    //   21..37  Qhi | 37..53 Qlo | 53..57 Khi | 57..61 Klo | 61..65 VbfT
    //   65      RSx (160KB) | 65.5  RSa (256KB)
    char* ws = (char*)d_ws;
    ushort* Xhi  = (ushort*)ws;
    ushort* AObf = (ushort*)ws;   // alias; Xhi/Xlo dead after qkv2
    ushort* Xlo  = (ushort*)(ws + (size_t)10 * 1024 * 1024 + 512 * 1024);
    ushort* Qhi  = (ushort*)(ws + (size_t)21 * 1024 * 1024);
    ushort* Qlo  = (ushort*)(ws + (size_t)37 * 1024 * 1024);
    ushort* Khi  = (ushort*)(ws + (size_t)53 * 1024 * 1024);
    ushort* Klo  = (ushort*)(ws + (size_t)57 * 1024 * 1024);
    ushort* VbfT = (ushort*)(ws + (size_t)61 * 1024 * 1024);
    float*  RSx  = (float*)(ws + (size_t)65 * 1024 * 1024);
    float*  RSa  = (float*)(ws + (size_t)65 * 1024 * 1024 + 512 * 1024);

    xsplit_rs_kernel<<<S_LEN, 320, 0, stream>>>(x, Xhi, Xlo, RSx);

    qkv2_kernel<<<768, 512, 0, stream>>>(
        Xhi, Xlo, RSx,
        q_qw, q_sc, q_qz, q_b,
        k_qw, k_sc, k_qz, k_b,
        v_qw, v_sc, v_qz, v_b,
        cosb, sinb, Qhi, Qlo, Khi, Klo, VbfT);

    attn_mfma_kernel<<<dim3(NH, S_LEN / 64), 256, 0, stream>>>(
        Qhi, Qlo, Khi, Klo, VbfT, AObf);

    rs_ao_kernel<<<S_LEN, 512, 0, stream>>>(AObf, RSa);

    oproj2_kernel<<<320, 512, 0, stream>>>(
        AObf, RSa, o_qw, o_sc, o_qz, out);
}

// Round 8
// 374.051 us; speedup vs baseline: 2.4397x; 1.2027x over previous
//
#include <hip/hip_runtime.h>
#include <hip/hip_bf16.h>
#include <cstdint>

#define S_LEN 2048
#define HIDDEN 2560
#define NH 32
#define NKV 8
#define HD 128
#define GS 128

typedef __attribute__((ext_vector_type(8))) short short8v;      // 8 x bf16
typedef __attribute__((ext_vector_type(8))) _Float16 half8v;    // 8 x fp16
typedef __attribute__((ext_vector_type(4))) float f32x4;
typedef unsigned int uint;
typedef unsigned short ushort;

__device__ inline ushort f2bf(float f) {
    uint u = __builtin_bit_cast(uint, f);
    u += 0x7fffu + ((u >> 16) & 1u);   // RNE
    return (ushort)(u >> 16);
}
__device__ inline float bf2f(ushort u) {
    return __builtin_bit_cast(float, (uint)u << 16);
}
__device__ inline ushort f2h(float f) {
    _Float16 h = (_Float16)f;
    return __builtin_bit_cast(ushort, h);
}
__device__ inline uint pk2(ushort a, ushort b) { return (uint)a | ((uint)b << 16); }

// async global->LDS, 16B per lane; lds base must be wave-uniform
__device__ __attribute__((always_inline)) inline void gl_lds16(const void* g, void* l) {
    __builtin_amdgcn_global_load_lds(
        (const __attribute__((address_space(1))) unsigned int*)g,
        (__attribute__((address_space(3))) unsigned int*)l, 16, 0, 0);
}

// ---------------------------------------------------------------------------
// X -> fp16 (single) + per-group(128) rowsums of the CONVERTED values.
// ---------------------------------------------------------------------------
__global__ __launch_bounds__(320) void xcvt_rs_kernel(
    const float* __restrict__ X, ushort* __restrict__ Xf,
    float* __restrict__ RSx)
{
    const int row = blockIdx.x;
    const int t   = threadIdx.x;
    const size_t base = (size_t)row * HIDDEN + t * 8;
    float4 a = *(const float4*)&X[base];
    float4 b = *(const float4*)&X[base + 4];
    float xv[8] = {a.x, a.y, a.z, a.w, b.x, b.y, b.z, b.w};
    ushort hv[8];
    float sum = 0.f;
#pragma unroll
    for (int j = 0; j < 8; ++j) {
        hv[j] = f2h(xv[j]);
        sum += (float)__builtin_bit_cast(_Float16, hv[j]);
    }
    uint4 hw = {pk2(hv[0], hv[1]), pk2(hv[2], hv[3]), pk2(hv[4], hv[5]), pk2(hv[6], hv[7])};
    *(uint4*)&Xf[base] = hw;
    sum += __shfl_xor(sum, 1);
    sum += __shfl_xor(sum, 2);
    sum += __shfl_xor(sum, 4);
    sum += __shfl_xor(sum, 8);
    if ((t & 15) == 0) RSx[(size_t)row * 20 + (t >> 4)] = sum;
}

// ---------------------------------------------------------------------------
// AO (bf16, exact) per-group rowsums RSa[row][32].
// ---------------------------------------------------------------------------
__global__ __launch_bounds__(512) void rs_ao_kernel(
    const ushort* __restrict__ AO, float* __restrict__ RSa)
{
    const int row = blockIdx.x;
    const int t   = threadIdx.x;
    uint4 v = *(const uint4*)&AO[(size_t)row * (NH * HD) + t * 8];
    const uint* pw = (const uint*)&v;
    float sum = 0.f;
#pragma unroll
    for (int j = 0; j < 4; ++j)
        sum += bf2f((ushort)(pw[j] & 0xffff)) + bf2f((ushort)(pw[j] >> 16));
    sum += __shfl_xor(sum, 1);
    sum += __shfl_xor(sum, 2);
    sum += __shfl_xor(sum, 4);
    sum += __shfl_xor(sum, 8);
    if ((t & 15) == 0) RSa[(size_t)row * 32 + (t >> 4)] = sum;
}

// ===========================================================================
// Fused Q/K/V AWQ-int4 MFMA GEMM (fp16 path), 2-phase double-buffer.
// B = (nib+128) EXACT fp16: 128+n = 2^7*(1+n/128) -> bits 0x5800 | (n<<3).
// y = sc*gacc - sc*(z+128)*RSx + bias.
// Block 128(M)x256(N), 512 thr / 8 waves (2Mx4N), wave tile 64x64.
// Wave col-remap puts RoPE partners {d, d+64} in the SAME lane.
// LDS: A dbuf 2x16KB + B dbuf 2x32KB = 96 KB.
// ===========================================================================
__global__ __launch_bounds__(512) void qkv3_kernel(
    const ushort* __restrict__ Xf, const float* __restrict__ RSx,
    const int* __restrict__ q_qw, const float* __restrict__ q_sc,
    const int* __restrict__ q_qz, const float* __restrict__ q_b,
    const int* __restrict__ k_qw, const float* __restrict__ k_sc,
    const int* __restrict__ k_qz, const float* __restrict__ k_b,
    const int* __restrict__ v_qw, const float* __restrict__ v_sc,
    const int* __restrict__ v_qz, const float* __restrict__ v_b,
    const float* __restrict__ cosb, const float* __restrict__ sinb,
    ushort* __restrict__ Qf, ushort* __restrict__ Kf,
    ushort* __restrict__ Vrm)
{
    __shared__ __align__(16) char LDSB[98304];
    ushort* A0  = (ushort*)(LDSB);
    ushort* A1  = (ushort*)(LDSB + 16384);
    ushort* Bt0 = (ushort*)(LDSB + 32768);
    ushort* Bt1 = (ushort*)(LDSB + 65536);

    const int t  = threadIdx.x;
    const int w  = t >> 6;
    const int l  = t & 63;
    const int lg = l >> 4;
    const int lr = l & 15;
    const int wr = w >> 2;       // 0..1 : M half
    const int wc = w & 3;        // 0..3 : N quarter
    const int K  = HIDDEN;

    // XCD-bijective swizzle: 384 = 8 * 48
    const int bid = blockIdx.x;
    const int swz = (bid & 7) * 48 + (bid >> 3);
    const int nblk = swz % 24;
    const int m0   = (swz / 24) * 128;

    int region, nbase, Nw;
    const int* QW; const float* SC; const int* QZ; const float* BI;
    if (nblk < 16)      { region = 0; nbase = nblk * 256;        Nw = NH * HD;
                          QW = q_qw; SC = q_sc; QZ = q_qz; BI = q_b; }
    else if (nblk < 20) { region = 1; nbase = (nblk - 16) * 256; Nw = NKV * HD;
                          QW = k_qw; SC = k_sc; QZ = k_qz; BI = k_b; }
    else                { region = 2; nbase = (nblk - 20) * 256; Nw = NKV * HD;
                          QW = v_qw; SC = v_sc; QZ = v_qz; BI = v_b; }

    // A staging (2 chunks of 16B per thread)
    const int am0 = t >> 3, ac0 = t & 7;
    const size_t aoff0 = (size_t)(m0 + am0) * K + (size_t)((ac0 ^ (am0 & 7)) * 8);
    const size_t aoff1 = aoff0 + (size_t)64 * K;
    const int ldsA0 = w * 1024;
    const int ldsA1 = 8192 + w * 1024;
    // B staging (4 qwords per thread)
    const int bn  = t & 255;
    const int bk0 = (t >> 8) * 4;
    int bwoff[4];
#pragma unroll
    for (int j = 0; j < 4; ++j)
        bwoff[j] = (bn * 128 + (bk0 + j) * 16) ^ ((bn & 7) << 4);

    // wave col remap (RoPE partners intra-lane)
    int ncm[4];
#pragma unroll
    for (int nf = 0; nf < 4; ++nf)
        ncm[nf] = (wc >> 1) * 128 + ((nf & 2) ? 64 : 0) + (wc & 1) * 32 + (nf & 1) * 16 + lr;

    const int xorA = (lr & 7) << 4;
    int aroff[4][2], broff[4][2];
#pragma unroll
    for (int mf = 0; mf < 4; ++mf)
#pragma unroll
        for (int ks = 0; ks < 2; ++ks)
            aroff[mf][ks] = (((wr * 64 + mf * 16 + lr) * 128) + lg * 16 + ks * 64) ^ xorA;
#pragma unroll
    for (int nf = 0; nf < 4; ++nf)
#pragma unroll
        for (int ks = 0; ks < 2; ++ks)
            broff[nf][ks] = ((ncm[nf] * 128) + lg * 16 + ks * 64) ^ xorA;

    f32x4 macc[4][4];
#pragma unroll
    for (int mf = 0; mf < 4; ++mf)
#pragma unroll
        for (int nf = 0; nf < 4; ++nf) macc[mf][nf] = f32x4{0.f, 0.f, 0.f, 0.f};
    f32x4 gacc[4][4];
    const f32x4 zc = f32x4{0.f, 0.f, 0.f, 0.f};
    uint qr[4];

#define QKV_QW(tile) { int g8 = (tile) * 8; \
    _Pragma("unroll") \
    for (int j = 0; j < 4; ++j) \
        qr[j] = (uint)QW[(size_t)(g8 + bk0 + j) * Nw + nbase + bn]; }

#define QKV_STAGE_A(AH, k0) { \
    gl_lds16(Xf + (k0) + aoff0, (char*)(AH) + ldsA0); \
    gl_lds16(Xf + (k0) + aoff1, (char*)(AH) + ldsA1); }

// fp16(128+n) = 0x5800 | (n<<3); pair: low nibble -> low ushort.
#define QKV_BWRITE(BT) { \
    _Pragma("unroll") \
    for (int j = 0; j < 4; ++j) { \
        uint q = qr[j]; \
        uint4 dw; \
        uint b0 = q & 0xFFu, b1 = (q >> 8) & 0xFFu, b2 = (q >> 16) & 0xFFu, b3 = q >> 24; \
        dw.x = 0x58005800u | ((b0 & 0xFu) << 3) | ((b0 & 0xF0u) << 15); \
        dw.y = 0x58005800u | ((b1 & 0xFu) << 3) | ((b1 & 0xF0u) << 15); \
        dw.z = 0x58005800u | ((b2 & 0xFu) << 3) | ((b2 & 0xF0u) << 15); \
        dw.w = 0x58005800u | ((b3 & 0xFu) << 3) | ((b3 & 0xF0u) << 15); \
        *(uint4*)((char*)(BT) + bwoff[j]) = dw; \
    } }

#define QKV_COMPUTE(AH, BT, INIT) { \
    _Pragma("unroll") \
    for (int ks = 0; ks < 2; ++ks) { \
        half8v av[4], bv[4]; \
        _Pragma("unroll") \
        for (int mf = 0; mf < 4; ++mf) \
            av[mf] = *(const half8v*)((const char*)(AH) + aroff[mf][ks]); \
        _Pragma("unroll") \
        for (int nf = 0; nf < 4; ++nf) \
            bv[nf] = *(const half8v*)((const char*)(BT) + broff[nf][ks]); \
        _Pragma("unroll") \
        for (int mf = 0; mf < 4; ++mf) \
            _Pragma("unroll") \
            for (int nf = 0; nf < 4; ++nf) { \
                f32x4 c = ((INIT) && ks == 0) ? zc : gacc[mf][nf]; \
                gacc[mf][nf] = __builtin_amdgcn_mfma_f32_16x16x32_f16(av[mf], bv[nf], c, 0, 0, 0); \
            } \
    } }

#define QKV_RESCALE(g) { \
    float rsv[4][4]; \
    _Pragma("unroll") \
    for (int mf = 0; mf < 4; ++mf) \
        _Pragma("unroll") \
        for (int r = 0; r < 4; ++r) \
            rsv[mf][r] = RSx[(size_t)(m0 + wr * 64 + mf * 16 + lg * 4 + r) * 20 + (g)]; \
    _Pragma("unroll") \
    for (int nf = 0; nf < 4; ++nf) { \
        int col = nbase + ncm[nf]; \
        float sc = SC[(size_t)(g) * Nw + col]; \
        float sz = sc * ((float)QZ[(size_t)(g) * Nw + col] + 128.0f); \
        _Pragma("unroll") \
        for (int mf = 0; mf < 4; ++mf) \
            _Pragma("unroll") \
            for (int r = 0; r < 4; ++r) \
                macc[mf][nf][r] += sc * gacc[mf][nf][r] - sz * rsv[mf][r]; \
    } }

    QKV_QW(0);
    QKV_STAGE_A(A0, 0);
    QKV_BWRITE(Bt0);
    __syncthreads();

    for (int g = 0; g < 20; ++g) {
        const int t1 = 2 * g + 1;
        QKV_QW(t1);
        QKV_STAGE_A(A1, t1 * 64);
        QKV_COMPUTE(A0, Bt0, true);
        QKV_BWRITE(Bt1);
        __syncthreads();
        if (g < 19) {
            const int t2 = 2 * g + 2;
            QKV_QW(t2);
            QKV_STAGE_A(A0, t2 * 64);
        }
        QKV_COMPUTE(A1, Bt1, false);
        if (g < 19) QKV_BWRITE(Bt0);
        QKV_RESCALE(g);
        __syncthreads();
    }

    // ---- +bias ----
#pragma unroll
    for (int nf = 0; nf < 4; ++nf) {
        float bv = BI[nbase + ncm[nf]];
#pragma unroll
        for (int mf = 0; mf < 4; ++mf)
#pragma unroll
            for (int r = 0; r < 4; ++r) macc[mf][nf][r] += bv;
    }

    // ---- epilogue ----
    if (region == 2) {
#pragma unroll
        for (int mf = 0; mf < 4; ++mf)
#pragma unroll
            for (int r = 0; r < 4; ++r) {
                int row = m0 + wr * 64 + mf * 16 + lg * 4 + r;
#pragma unroll
                for (int nf = 0; nf < 4; ++nf)
                    Vrm[(size_t)row * (NKV * HD) + nbase + ncm[nf]] = f2h(macc[mf][nf][r]);
            }
    } else {
        ushort* OF = (region == 0) ? Qf : Kf;
        const int No = (region == 0) ? NH * HD : NKV * HD;
        const float osc = (region == 0) ? 0.08838834764831845f : 1.0f;
        const int colb = nbase + (wc >> 1) * 128;
#pragma unroll
        for (int mf = 0; mf < 4; ++mf)
#pragma unroll
            for (int r = 0; r < 4; ++r) {
                int row = m0 + wr * 64 + mf * 16 + lg * 4 + r;
                const float* cb = &cosb[(size_t)row * HD];
                const float* sb = &sinb[(size_t)row * HD];
#pragma unroll
                for (int nf = 0; nf < 2; ++nf) {
                    int d = (wc & 1) * 32 + nf * 16 + lr;     // 0..63
                    float a = macc[mf][nf][r];
                    float b = macc[mf][nf + 2][r];
                    float o1 = (a * cb[d]      - b * sb[d])      * osc;
                    float o2 = (b * cb[d + 64] + a * sb[d + 64]) * osc;
                    OF[(size_t)row * No + colb + d]      = f2h(o1);
                    OF[(size_t)row * No + colb + d + 64] = f2h(o2);
                }
            }
    }
#undef QKV_QW
#undef QKV_STAGE_A
#undef QKV_BWRITE
#undef QKV_COMPUTE
#undef QKV_RESCALE
}

// ---------------------------------------------------------------------------
// V transpose: Vrm [S][1024] fp16 -> VfT [1024][S]. 64x64 LDS tiles.
// ---------------------------------------------------------------------------
__global__ __launch_bounds__(256) void vtrans_kernel(
    const ushort* __restrict__ Vrm, ushort* __restrict__ VfT)
{
    __shared__ ushort Ts[64][65];
    const int s0 = blockIdx.x * 64;
    const int n0 = blockIdx.y * 64;
    const int t  = threadIdx.x;
    {
        int r = t >> 2, c0 = (t & 3) * 16;
        uint4 v0 = *(const uint4*)&Vrm[(size_t)(s0 + r) * (NKV * HD) + n0 + c0];
        uint4 v1 = *(const uint4*)&Vrm[(size_t)(s0 + r) * (NKV * HD) + n0 + c0 + 8];
        const ushort* pv = (const ushort*)&v0;
#pragma unroll
        for (int j = 0; j < 8; ++j) Ts[r][c0 + j] = pv[j];
        pv = (const ushort*)&v1;
#pragma unroll
        for (int j = 0; j < 8; ++j) Ts[r][c0 + 8 + j] = pv[j];
    }
    __syncthreads();
    {
        int rn = t >> 2, cs0 = (t & 3) * 16;
        ushort ob[16];
#pragma unroll
        for (int j = 0; j < 16; ++j) ob[j] = Ts[cs0 + j][rn];
        ushort* dst = &VfT[(size_t)(n0 + rn) * S_LEN + s0 + cs0];
        *(uint4*)dst = ((uint4*)ob)[0];
        *(uint4*)(dst + 8) = ((uint4*)ob)[1];
    }
}

// ===========================================================================
// O-projection (bf16 exact path), wave 64x64, 2-phase pipeline.
// Block 128x256, grid 160. B = (nib+128) exact bf16 (0x4300 | n).
// ===========================================================================
__global__ __launch_bounds__(512) void oproj3_kernel(
    const ushort* __restrict__ Xb, const float* __restrict__ RSa,
    const int* __restrict__ QW, const float* __restrict__ SC,
    const int* __restrict__ QZ, float* __restrict__ Y)
{
    __shared__ __align__(16) char LDSB[98304];
    ushort* A0  = (ushort*)(LDSB);
    ushort* A1  = (ushort*)(LDSB + 16384);
    ushort* Bt0 = (ushort*)(LDSB + 32768);
    ushort* Bt1 = (ushort*)(LDSB + 65536);

    const int t  = threadIdx.x;
    const int w  = t >> 6;
    const int l  = t & 63;
    const int lg = l >> 4;
    const int lr = l & 15;
    const int wr = w >> 2;
    const int wc = w & 3;
    const int K  = NH * HD;      // 4096
    const int N  = HIDDEN;       // 2560

    const int bid = blockIdx.x;
    const int swz = (bid & 7) * 20 + (bid >> 3);   // 160 = 8*20
    const int n0  = (swz % 10) * 256;
    const int m0  = (swz / 10) * 128;

    const int am0 = t >> 3, ac0 = t & 7;
    const size_t aoff0 = (size_t)(m0 + am0) * K + (size_t)((ac0 ^ (am0 & 7)) * 8);
    const size_t aoff1 = aoff0 + (size_t)64 * K;
    const int ldsA0 = w * 1024;
    const int ldsA1 = 8192 + w * 1024;
    const int bn  = t & 255;
    const int bk0 = (t >> 8) * 4;
    int bwoff[4];
#pragma unroll
    for (int j = 0; j < 4; ++j)
        bwoff[j] = (bn * 128 + (bk0 + j) * 16) ^ ((bn & 7) << 4);

    const int xorA = (lr & 7) << 4;
    int aroff[4][2], broff[4][2];
#pragma unroll
    for (int mf = 0; mf < 4; ++mf)
#pragma unroll
        for (int ks = 0; ks < 2; ++ks)
            aroff[mf][ks] = (((wr * 64 + mf * 16 + lr) * 128) + lg * 16 + ks * 64) ^ xorA;
#pragma unroll
    for (int nf = 0; nf < 4; ++nf)
#pragma unroll
        for (int ks = 0; ks < 2; ++ks)
            broff[nf][ks] = (((wc * 64 + nf * 16 + lr) * 128) + lg * 16 + ks * 64) ^ xorA;

    f32x4 macc[4][4];
#pragma unroll
    for (int mf = 0; mf < 4; ++mf)
#pragma unroll
        for (int nf = 0; nf < 4; ++nf) macc[mf][nf] = f32x4{0.f, 0.f, 0.f, 0.f};
    f32x4 gacc[4][4];
    const f32x4 zc = f32x4{0.f, 0.f, 0.f, 0.f};
    uint qr[4];

#define OP_QW(tile) { int g8 = (tile) * 8; \
    _Pragma("unroll") \
    for (int j = 0; j < 4; ++j) \
        qr[j] = (uint)QW[(size_t)(g8 + bk0 + j) * N + n0 + bn]; }

#define OP_STAGE_A(AH, k0) { \
    gl_lds16(Xb + (k0) + aoff0, (char*)(AH) + ldsA0); \
    gl_lds16(Xb + (k0) + aoff1, (char*)(AH) + ldsA1); }

#define OP_BWRITE(BT) { \
    _Pragma("unroll") \
    for (int j = 0; j < 4; ++j) { \
        uint q = qr[j]; \
        uint4 dw; \
        uint b0 = q & 0xFFu, b1 = (q >> 8) & 0xFFu, b2 = (q >> 16) & 0xFFu, b3 = q >> 24; \
        dw.x = 0x43004300u | (b0 & 0xFu) | ((b0 & 0xF0u) << 12); \
        dw.y = 0x43004300u | (b1 & 0xFu) | ((b1 & 0xF0u) << 12); \
        dw.z = 0x43004300u | (b2 & 0xFu) | ((b2 & 0xF0u) << 12); \
        dw.w = 0x43004300u | (b3 & 0xFu) | ((b3 & 0xF0u) << 12); \
        *(uint4*)((char*)(BT) + bwoff[j]) = dw; \
    } }

#define OP_COMPUTE(AH, BT, INIT) { \
    _Pragma("unroll") \
    for (int ks = 0; ks < 2; ++ks) { \
        short8v av[4], bv[4]; \
        _Pragma("unroll") \
        for (int mf = 0; mf < 4; ++mf) \
            av[mf] = *(const short8v*)((const char*)(AH) + aroff[mf][ks]); \
        _Pragma("unroll") \
        for (int nf = 0; nf < 4; ++nf) \
            bv[nf] = *(const short8v*)((const char*)(BT) + broff[nf][ks]); \
        _Pragma("unroll") \
        for (int mf = 0; mf < 4; ++mf) \
            _Pragma("unroll") \
            for (int nf = 0; nf < 4; ++nf) { \
                f32x4 c = ((INIT) && ks == 0) ? zc : gacc[mf][nf]; \
                gacc[mf][nf] = __builtin_amdgcn_mfma_f32_16x16x32_bf16(av[mf], bv[nf], c, 0, 0, 0); \
            } \
    } }

#define OP_RESCALE(g) { \
    float rsv[4][4]; \
    _Pragma("unroll") \
    for (int mf = 0; mf < 4; ++mf) \
        _Pragma("unroll") \
        for (int r = 0; r < 4; ++r) \
            rsv[mf][r] = RSa[(size_t)(m0 + wr * 64 + mf * 16 + lg * 4 + r) * 32 + (g)]; \
    _Pragma("unroll") \
    for (int nf = 0; nf < 4; ++nf) { \
        int col = n0 + wc * 64 + nf * 16 + lr; \
        float sc = SC[(size_t)(g) * N + col]; \
        float sz = sc * ((float)QZ[(size_t)(g) * N + col] + 128.0f); \
        _Pragma("unroll") \
        for (int mf = 0; mf < 4; ++mf) \
            _Pragma("unroll") \
            for (int r = 0; r < 4; ++r) \
                macc[mf][nf][r] += sc * gacc[mf][nf][r] - sz * rsv[mf][r]; \
    } }

    OP_QW(0);
    OP_STAGE_A(A0, 0);
    OP_BWRITE(Bt0);
    __syncthreads();

    for (int g = 0; g < 32; ++g) {
        const int t1 = 2 * g + 1;
        OP_QW(t1);
        OP_STAGE_A(A1, t1 * 64);
        OP_COMPUTE(A0, Bt0, true);
        OP_BWRITE(Bt1);
        __syncthreads();
        if (g < 31) {
            const int t2 = 2 * g + 2;
            OP_QW(t2);
            OP_STAGE_A(A0, t2 * 64);
        }
        OP_COMPUTE(A1, Bt1, false);
        if (g < 31) OP_BWRITE(Bt0);
        OP_RESCALE(g);
        __syncthreads();
    }

#pragma unroll
    for (int mf = 0; mf < 4; ++mf)
#pragma unroll
        for (int r = 0; r < 4; ++r) {
            int row = m0 + wr * 64 + mf * 16 + lg * 4 + r;
#pragma unroll
            for (int nf = 0; nf < 4; ++nf)
                Y[(size_t)row * N + n0 + wc * 64 + nf * 16 + lr] = macc[mf][nf][r];
        }
#undef OP_QW
#undef OP_STAGE_A
#undef OP_BWRITE
#undef OP_COMPUTE
#undef OP_RESCALE
}

// ---------------------------------------------------------------------------
// Causal GQA flash attention, fp16 MFMA (single QK^T MFMA; fp16 P,V).
// ---------------------------------------------------------------------------
__global__ __launch_bounds__(256) void attn_mfma_kernel(
    const ushort* __restrict__ Qh,   // [S][NH*HD] fp16, roped, *1/sqrt(HD)
    const ushort* __restrict__ Kh,   // [S][NKV*HD] fp16, roped
    const ushort* __restrict__ Vt,   // [NKV*HD][S] fp16 (transposed)
    ushort* __restrict__ AO)         // [S][NH*HD] bf16
{
    __shared__ ushort KsF[32 * 128];   // 8 KB, swz ^((row&7)<<4)
    __shared__ ushort Vs[128 * 32];    // 8 KB, swz ^((dim&3)<<4)
    __shared__ ushort Ps[4][16 * 32];  // fp16 P, swz ^((row&3)<<4)

    const int h  = blockIdx.x;
    const int qb = gridDim.y - 1 - blockIdx.y;
    const int s0 = qb * 64;
    const int t  = threadIdx.x;
    const int w  = t >> 6;
    const int l  = t & 63;
    const int lg = l >> 4;
    const int lr = l & 15;
    const int kvh = h >> 2;
    const int qw = s0 + w * 16;

    half8v qf[4];
#pragma unroll
    for (int d = 0; d < 4; ++d) {
        size_t off = (size_t)(qw + lr) * (NH * HD) + h * HD + d * 32 + lg * 8;
        qf[d] = *(const half8v*)&Qh[off];
    }

    f32x4 o[8];
#pragma unroll
    for (int i = 0; i < 8; ++i) o[i] = f32x4{0.f, 0.f, 0.f, 0.f};
    float m[4], lsum[4];
#pragma unroll
    for (int r = 0; r < 4; ++r) { m[r] = -1e30f; lsum[r] = 0.f; }

    const int ntiles = qb * 2 + 2;
    for (int kt = 0; kt < ntiles; ++kt) {
        const int k0 = kt * 32;
#pragma unroll
        for (int i = 0; i < 2; ++i) {
            int slot = w * 128 + i * 64 + l;
            int mr = slot >> 4, c = slot & 15;
            size_t goff = (size_t)(k0 + mr) * (NKV * HD) + kvh * HD + ((c ^ (mr & 7)) * 8);
            gl_lds16(Kh + goff, (char*)KsF + (w * 128 + i * 64) * 16);
        }
#pragma unroll
        for (int i = 0; i < 2; ++i) {
            int slot = w * 128 + i * 64 + l;
            int dim = slot >> 2, c = slot & 3;
            size_t goff = (size_t)(kvh * HD + dim) * S_LEN + k0 + ((c ^ (dim & 3)) * 8);
            gl_lds16(Vt + goff, (char*)Vs + (w * 128 + i * 64) * 16);
        }
        __syncthreads();

        if (k0 <= qw + 15) {
            f32x4 s[2];
            s[0] = f32x4{0.f, 0.f, 0.f, 0.f};
            s[1] = f32x4{0.f, 0.f, 0.f, 0.f};
#pragma unroll
            for (int d = 0; d < 4; ++d) {
#pragma unroll
                for (int nt2 = 0; nt2 < 2; ++nt2) {
                    int row = nt2 * 16 + lr;
                    int off = row * 256 + ((d * 64 + lg * 16) ^ ((row & 7) << 4));
                    half8v kf = *(const half8v*)((char*)KsF + off);
                    s[nt2] = __builtin_amdgcn_mfma_f32_16x16x32_f16(qf[d], kf, s[nt2], 0, 0, 0);
                }
            }
            float p0a[4], p1a[4], resc[4];
#pragma unroll
            for (int r = 0; r < 4; ++r) {
                int qrow = qw + lg * 4 + r;
                float s0v = (k0 + lr      <= qrow) ? s[0][r] : -1e30f;
                float s1v = (k0 + 16 + lr <= qrow) ? s[1][r] : -1e30f;
                float mx = fmaxf(s0v, s1v);
                mx = fmaxf(mx, __shfl_xor(mx, 1));
                mx = fmaxf(mx, __shfl_xor(mx, 2));
                mx = fmaxf(mx, __shfl_xor(mx, 4));
                mx = fmaxf(mx, __shfl_xor(mx, 8));
                float mnew = fmaxf(m[r], mx);
                resc[r] = __expf(m[r] - mnew);
                m[r] = mnew;
                float p0 = __expf(s0v - mnew);
                float p1 = __expf(s1v - mnew);
                p0a[r] = p0; p1a[r] = p1;
                float ps = p0 + p1;
                ps += __shfl_xor(ps, 1);
                ps += __shfl_xor(ps, 2);
                ps += __shfl_xor(ps, 4);
                ps += __shfl_xor(ps, 8);
                lsum[r] = lsum[r] * resc[r] + ps;
            }
#pragma unroll
            for (int dt = 0; dt < 8; ++dt)
#pragma unroll
                for (int r = 0; r < 4; ++r) o[dt][r] *= resc[r];
            ushort* pw = Ps[w];
#pragma unroll
            for (int r = 0; r < 4; ++r) {
                int row = lg * 4 + r;
                *(ushort*)((char*)pw + row * 64 + (((lr)      * 2) ^ ((row & 3) << 4))) = f2h(p0a[r]);
                *(ushort*)((char*)pw + row * 64 + (((lr + 16) * 2) ^ ((row & 3) << 4))) = f2h(p1a[r]);
            }
            asm volatile("s_waitcnt lgkmcnt(0)" ::: "memory");
            half8v pf = *(const half8v*)((char*)pw + lr * 64 + ((lg * 16) ^ ((lr & 3) << 4)));
#pragma unroll
            for (int dt = 0; dt < 8; ++dt) {
                int dim = dt * 16 + lr;
                half8v vf = *(const half8v*)((char*)Vs + dim * 64 + ((lg * 16) ^ ((dim & 3) << 4)));
                o[dt] = __builtin_amdgcn_mfma_f32_16x16x32_f16(pf, vf, o[dt], 0, 0, 0);
            }
        }
        __syncthreads();
    }

#pragma unroll
    for (int r = 0; r < 4; ++r) {
        float inv = 1.f / lsum[r];
        int qrow = qw + lg * 4 + r;
        ushort* dst = &AO[(size_t)qrow * (NH * HD) + h * HD];
#pragma unroll
        for (int dt = 0; dt < 8; ++dt) dst[dt * 16 + lr] = f2bf(o[dt][r] * inv);
    }
}

// ---------------------------------------------------------------------------
extern "C" void kernel_launch(void* const* d_in, const int* in_sizes, int n_in,
                              void* d_out, int out_size, void* d_ws, size_t ws_size,
                              hipStream_t stream)
{
    const float* x    = (const float*)d_in[0];
    const float* cosb = (const float*)d_in[1];
    const float* sinb = (const float*)d_in[2];
    const float* q_sc = (const float*)d_in[3];
    const float* q_b  = (const float*)d_in[4];
    const float* k_sc = (const float*)d_in[5];
    const float* k_b  = (const float*)d_in[6];
    const float* v_sc = (const float*)d_in[7];
    const float* v_b  = (const float*)d_in[8];
    const float* o_sc = (const float*)d_in[9];
    const int* q_qw   = (const int*)d_in[10];
    const int* q_qz   = (const int*)d_in[11];
    const int* k_qw   = (const int*)d_in[12];
    const int* k_qz   = (const int*)d_in[13];
    const int* v_qw   = (const int*)d_in[14];
    const int* v_qz   = (const int*)d_in[15];
    const int* o_qw   = (const int*)d_in[16];
    const int* o_qz   = (const int*)d_in[17];
    float* out = (float*)d_out;

    // ws layout (MB):
    //   0:  Xf16 (10)  [aliased by AObf16 (16) after qkv3]
    //   16: Qf (16) | 32: Kf (4) | 36: Vrm (4) | 40: VfT (4)
    //   44: RSx (160KB) | 45: RSa (256KB)
    char* ws = (char*)d_ws;
    ushort* Xf   = (ushort*)ws;
    ushort* AObf = (ushort*)ws;                                  // alias
    ushort* Qf   = (ushort*)(ws + (size_t)16 * 1024 * 1024);
    ushort* Kf   = (ushort*)(ws + (size_t)32 * 1024 * 1024);
    ushort* Vrm  = (ushort*)(ws + (size_t)36 * 1024 * 1024);
    ushort* VfT  = (ushort*)(ws + (size_t)40 * 1024 * 1024);
    float*  RSx  = (float*)(ws + (size_t)44 * 1024 * 1024);
    float*  RSa  = (float*)(ws + (size_t)45 * 1024 * 1024);

    xcvt_rs_kernel<<<S_LEN, 320, 0, stream>>>(x, Xf, RSx);

    qkv3_kernel<<<384, 512, 0, stream>>>(
        Xf, RSx,
        q_qw, q_sc, q_qz, q_b,
        k_qw, k_sc, k_qz, k_b,
        v_qw, v_sc, v_qz, v_b,
        cosb, sinb, Qf, Kf, Vrm);

    vtrans_kernel<<<dim3(S_LEN / 64, (NKV * HD) / 64), 256, 0, stream>>>(Vrm, VfT);

    attn_mfma_kernel<<<dim3(NH, S_LEN / 64), 256, 0, stream>>>(Qf, Kf, VfT, AObf);

    rs_ao_kernel<<<S_LEN, 512, 0, stream>>>(AObf, RSa);

    oproj3_kernel<<<160, 512, 0, stream>>>(
        AObf, RSa, o_qw, o_sc, o_qz, out);
}

// Round 9
// 324.629 us; speedup vs baseline: 2.8111x; 1.1522x over previous
//
#include <hip/hip_runtime.h>
#include <hip/hip_bf16.h>
#include <cstdint>

#define S_LEN 2048
#define HIDDEN 2560
#define NH 32
#define NKV 8
#define HD 128
#define GS 128

typedef __attribute__((ext_vector_type(8))) _Float16 half8v;    // 8 x fp16
typedef __attribute__((ext_vector_type(2))) _Float16 half2v;    // 2 x fp16
typedef __attribute__((ext_vector_type(4))) float f32x4;
typedef unsigned int uint;
typedef unsigned short ushort;

__device__ inline ushort f2h(float f) {
    _Float16 h = (_Float16)f;
    return __builtin_bit_cast(ushort, h);
}
__device__ inline float h2f(ushort u) {
    return (float)__builtin_bit_cast(_Float16, u);
}
__device__ inline uint pk2(ushort a, ushort b) { return (uint)a | ((uint)b << 16); }

// async global->LDS, 16B per lane; lds base must be wave-uniform
__device__ __attribute__((always_inline)) inline void gl_lds16(const void* g, void* l) {
    __builtin_amdgcn_global_load_lds(
        (const __attribute__((address_space(1))) unsigned int*)g,
        (__attribute__((address_space(3))) unsigned int*)l, 16, 0, 0);
}

// ---------------------------------------------------------------------------
// X -> fp16. One block per row, 320 thr x 8 els.
// ---------------------------------------------------------------------------
__global__ __launch_bounds__(320) void xcvt_kernel(
    const float* __restrict__ X, ushort* __restrict__ Xf)
{
    const int row = blockIdx.x;
    const int t   = threadIdx.x;
    const size_t base = (size_t)row * HIDDEN + t * 8;
    float4 a = *(const float4*)&X[base];
    float4 b = *(const float4*)&X[base + 4];
    uint4 hw = {pk2(f2h(a.x), f2h(a.y)), pk2(f2h(a.z), f2h(a.w)),
                pk2(f2h(b.x), f2h(b.y)), pk2(f2h(b.z), f2h(b.w))};
    *(uint4*)&Xf[base] = hw;
}

// ===========================================================================
// Fused Q/K/V AWQ-int4 MFMA GEMM, fp16 direct-scaled B, 2-phase dbuf.
// enc = fp16(128+nib) = 0x5800 | nib<<3 (exact).
// w = pk_fma(enc, sc_h, -128*sc_h) + (-z*sc_h)   [-128*sc_h exact exp-shift]
// Block 128Mx256N, 512 thr / 8 waves (2Mx4N), wave tile 64x64.
// Wave col-remap puts RoPE partners {d, d+64} in the SAME lane.
// LDS: A dbuf 2x16KB + B dbuf 2x32KB = 96 KB.
// ===========================================================================
__global__ __launch_bounds__(512) void qkv4_kernel(
    const ushort* __restrict__ Xf,
    const int* __restrict__ q_qw, const float* __restrict__ q_sc,
    const int* __restrict__ q_qz, const float* __restrict__ q_b,
    const int* __restrict__ k_qw, const float* __restrict__ k_sc,
    const int* __restrict__ k_qz, const float* __restrict__ k_b,
    const int* __restrict__ v_qw, const float* __restrict__ v_sc,
    const int* __restrict__ v_qz, const float* __restrict__ v_b,
    const float* __restrict__ cosb, const float* __restrict__ sinb,
    ushort* __restrict__ Qf, ushort* __restrict__ Kf,
    ushort* __restrict__ Vrm)
{
    __shared__ __align__(16) char LDSB[98304];
    ushort* A0  = (ushort*)(LDSB);
    ushort* A1  = (ushort*)(LDSB + 16384);
    ushort* Bt0 = (ushort*)(LDSB + 32768);
    ushort* Bt1 = (ushort*)(LDSB + 65536);

    const int t  = threadIdx.x;
    const int w  = t >> 6;
    const int l  = t & 63;
    const int lg = l >> 4;
    const int lr = l & 15;
    const int wr = w >> 2;       // M half
    const int wc = w & 3;        // N quarter
    const int K  = HIDDEN;

    // XCD-bijective swizzle: 384 = 8 * 48
    const int bid = blockIdx.x;
    const int swz = (bid & 7) * 48 + (bid >> 3);
    const int nblk = swz % 24;
    const int m0   = (swz / 24) * 128;

    int region, nbase, Nw;
    const int* QW; const float* SC; const int* QZ; const float* BI;
    if (nblk < 16)      { region = 0; nbase = nblk * 256;        Nw = NH * HD;
                          QW = q_qw; SC = q_sc; QZ = q_qz; BI = q_b; }
    else if (nblk < 20) { region = 1; nbase = (nblk - 16) * 256; Nw = NKV * HD;
                          QW = k_qw; SC = k_sc; QZ = k_qz; BI = k_b; }
    else                { region = 2; nbase = (nblk - 20) * 256; Nw = NKV * HD;
                          QW = v_qw; SC = v_sc; QZ = v_qz; BI = v_b; }

    // A staging (2 chunks of 16B per thread)
    const int am0 = t >> 3, ac0 = t & 7;
    const size_t aoff0 = (size_t)(m0 + am0) * K + (size_t)((ac0 ^ (am0 & 7)) * 8);
    const size_t aoff1 = aoff0 + (size_t)64 * K;
    const int ldsA0 = w * 1024;
    const int ldsA1 = 8192 + w * 1024;
    // B staging (4 qwords per thread, one column bn, krows bk0..bk0+3)
    const int bn  = t & 255;
    const int bk0 = (t >> 8) * 4;
    int bwoff[4];
#pragma unroll
    for (int j = 0; j < 4; ++j)
        bwoff[j] = (bn * 128 + (bk0 + j) * 16) ^ ((bn & 7) << 4);

    // wave col remap (RoPE partners intra-lane)
    int ncm[4];
#pragma unroll
    for (int nf = 0; nf < 4; ++nf)
        ncm[nf] = (wc >> 1) * 128 + ((nf & 2) ? 64 : 0) + (wc & 1) * 32 + (nf & 1) * 16 + lr;

    const int xorA = (lr & 7) << 4;
    int aroff[4][2], broff[4][2];
#pragma unroll
    for (int mf = 0; mf < 4; ++mf)
#pragma unroll
        for (int ks = 0; ks < 2; ++ks)
            aroff[mf][ks] = (((wr * 64 + mf * 16 + lr) * 128) + lg * 16 + ks * 64) ^ xorA;
#pragma unroll
    for (int nf = 0; nf < 4; ++nf)
#pragma unroll
        for (int ks = 0; ks < 2; ++ks)
            broff[nf][ks] = ((ncm[nf] * 128) + lg * 16 + ks * 64) ^ xorA;

    f32x4 macc[4][4];
#pragma unroll
    for (int mf = 0; mf < 4; ++mf)
#pragma unroll
        for (int nf = 0; nf < 4; ++nf) macc[mf][nf] = f32x4{0.f, 0.f, 0.f, 0.f};
    uint qr[4];
    float scf, zf;

#define QKV_QW(tile) { int g8 = (tile) * 8; int gg = (tile) >> 1; \
    _Pragma("unroll") \
    for (int j = 0; j < 4; ++j) \
        qr[j] = (uint)QW[(size_t)(g8 + bk0 + j) * Nw + nbase + bn]; \
    scf = SC[(size_t)gg * Nw + nbase + bn]; \
    zf  = (float)QZ[(size_t)gg * Nw + nbase + bn]; }

#define QKV_STAGE_A(AH, k0) { \
    gl_lds16(Xf + (k0) + aoff0, (char*)(AH) + ldsA0); \
    gl_lds16(Xf + (k0) + aoff1, (char*)(AH) + ldsA1); }

#define QKV_BWRITE(BT) { \
    ushort sch = f2h(scf); \
    float schf = h2f(sch); \
    ushort msc = f2h(-128.0f * schf);   /* exact exponent shift */ \
    ushort nzs = f2h(-(zf * schf)); \
    half2v S2 = {__builtin_bit_cast(_Float16, sch), __builtin_bit_cast(_Float16, sch)}; \
    half2v M2 = {__builtin_bit_cast(_Float16, msc), __builtin_bit_cast(_Float16, msc)}; \
    half2v Z2 = {__builtin_bit_cast(_Float16, nzs), __builtin_bit_cast(_Float16, nzs)}; \
    _Pragma("unroll") \
    for (int j = 0; j < 4; ++j) { \
        uint q = qr[j]; \
        uint b0 = q & 0xFFu, b1 = (q >> 8) & 0xFFu, b2 = (q >> 16) & 0xFFu, b3 = q >> 24; \
        uint e0 = 0x58005800u | ((b0 & 0xFu) << 3) | ((b0 & 0xF0u) << 15); \
        uint e1 = 0x58005800u | ((b1 & 0xFu) << 3) | ((b1 & 0xF0u) << 15); \
        uint e2 = 0x58005800u | ((b2 & 0xFu) << 3) | ((b2 & 0xF0u) << 15); \
        uint e3 = 0x58005800u | ((b3 & 0xFu) << 3) | ((b3 & 0xF0u) << 15); \
        half2v w0 = __builtin_bit_cast(half2v, e0) * S2 + M2; w0 = w0 + Z2; \
        half2v w1 = __builtin_bit_cast(half2v, e1) * S2 + M2; w1 = w1 + Z2; \
        half2v w2 = __builtin_bit_cast(half2v, e2) * S2 + M2; w2 = w2 + Z2; \
        half2v w3 = __builtin_bit_cast(half2v, e3) * S2 + M2; w3 = w3 + Z2; \
        uint4 dw = {__builtin_bit_cast(uint, w0), __builtin_bit_cast(uint, w1), \
                    __builtin_bit_cast(uint, w2), __builtin_bit_cast(uint, w3)}; \
        *(uint4*)((char*)(BT) + bwoff[j]) = dw; \
    } }

#define QKV_COMPUTE(AH, BT) { \
    _Pragma("unroll") \
    for (int ks = 0; ks < 2; ++ks) { \
        half8v av[4], bv[4]; \
        _Pragma("unroll") \
        for (int mf = 0; mf < 4; ++mf) \
            av[mf] = *(const half8v*)((const char*)(AH) + aroff[mf][ks]); \
        _Pragma("unroll") \
        for (int nf = 0; nf < 4; ++nf) \
            bv[nf] = *(const half8v*)((const char*)(BT) + broff[nf][ks]); \
        _Pragma("unroll") \
        for (int mf = 0; mf < 4; ++mf) \
            _Pragma("unroll") \
            for (int nf = 0; nf < 4; ++nf) \
                macc[mf][nf] = __builtin_amdgcn_mfma_f32_16x16x32_f16(av[mf], bv[nf], macc[mf][nf], 0, 0, 0); \
    } }

    QKV_QW(0);
    QKV_STAGE_A(A0, 0);
    QKV_BWRITE(Bt0);
    __syncthreads();

    for (int g = 0; g < 20; ++g) {
        const int t1 = 2 * g + 1;
        QKV_QW(t1);
        QKV_STAGE_A(A1, t1 * 64);
        QKV_COMPUTE(A0, Bt0);
        QKV_BWRITE(Bt1);
        __syncthreads();
        if (g < 19) {
            const int t2 = 2 * g + 2;
            QKV_QW(t2);
            QKV_STAGE_A(A0, t2 * 64);
        }
        QKV_COMPUTE(A1, Bt1);
        if (g < 19) QKV_BWRITE(Bt0);
        __syncthreads();
    }

    // ---- +bias ----
#pragma unroll
    for (int nf = 0; nf < 4; ++nf) {
        float bv = BI[nbase + ncm[nf]];
#pragma unroll
        for (int mf = 0; mf < 4; ++mf)
#pragma unroll
            for (int r = 0; r < 4; ++r) macc[mf][nf][r] += bv;
    }

    // ---- epilogue ----
    if (region == 2) {
#pragma unroll
        for (int mf = 0; mf < 4; ++mf)
#pragma unroll
            for (int r = 0; r < 4; ++r) {
                int row = m0 + wr * 64 + mf * 16 + lg * 4 + r;
#pragma unroll
                for (int nf = 0; nf < 4; ++nf)
                    Vrm[(size_t)row * (NKV * HD) + nbase + ncm[nf]] = f2h(macc[mf][nf][r]);
            }
    } else {
        ushort* OF = (region == 0) ? Qf : Kf;
        const int No = (region == 0) ? NH * HD : NKV * HD;
        const float osc = (region == 0) ? 0.08838834764831845f : 1.0f;
        const int colb = nbase + (wc >> 1) * 128;
#pragma unroll
        for (int mf = 0; mf < 4; ++mf)
#pragma unroll
            for (int r = 0; r < 4; ++r) {
                int row = m0 + wr * 64 + mf * 16 + lg * 4 + r;
                const float* cb = &cosb[(size_t)row * HD];
                const float* sb = &sinb[(size_t)row * HD];
#pragma unroll
                for (int nf = 0; nf < 2; ++nf) {
                    int d = (wc & 1) * 32 + nf * 16 + lr;     // 0..63
                    float a = macc[mf][nf][r];
                    float b = macc[mf][nf + 2][r];
                    float o1 = (a * cb[d]      - b * sb[d])      * osc;
                    float o2 = (b * cb[d + 64] + a * sb[d + 64]) * osc;
                    OF[(size_t)row * No + colb + d]      = f2h(o1);
                    OF[(size_t)row * No + colb + d + 64] = f2h(o2);
                }
            }
    }
#undef QKV_QW
#undef QKV_STAGE_A
#undef QKV_BWRITE
#undef QKV_COMPUTE
}

// ---------------------------------------------------------------------------
// V transpose: Vrm [S][1024] fp16 -> VfT [1024][S]. 64x64 LDS tiles.
// ---------------------------------------------------------------------------
__global__ __launch_bounds__(256) void vtrans_kernel(
    const ushort* __restrict__ Vrm, ushort* __restrict__ VfT)
{
    __shared__ ushort Ts[64][65];
    const int s0 = blockIdx.x * 64;
    const int n0 = blockIdx.y * 64;
    const int t  = threadIdx.x;
    {
        int r = t >> 2, c0 = (t & 3) * 16;
        uint4 v0 = *(const uint4*)&Vrm[(size_t)(s0 + r) * (NKV * HD) + n0 + c0];
        uint4 v1 = *(const uint4*)&Vrm[(size_t)(s0 + r) * (NKV * HD) + n0 + c0 + 8];
        const ushort* pv = (const ushort*)&v0;
#pragma unroll
        for (int j = 0; j < 8; ++j) Ts[r][c0 + j] = pv[j];
        pv = (const ushort*)&v1;
#pragma unroll
        for (int j = 0; j < 8; ++j) Ts[r][c0 + 8 + j] = pv[j];
    }
    __syncthreads();
    {
        int rn = t >> 2, cs0 = (t & 3) * 16;
        ushort ob[16];
#pragma unroll
        for (int j = 0; j < 16; ++j) ob[j] = Ts[cs0 + j][rn];
        ushort* dst = &VfT[(size_t)(n0 + rn) * S_LEN + s0 + cs0];
        *(uint4*)dst = ((uint4*)ob)[0];
        *(uint4*)(dst + 8) = ((uint4*)ob)[1];
    }
}

// ===========================================================================
// O-projection, fp16 direct-scaled B, 2-phase dbuf.
// Block 128Mx128N, 512 thr / 8 waves (2Mx4N), wave tile 64x32.
// LDS: A dbuf 2x16KB + B dbuf 2x16KB = 64 KB -> 2 blocks/CU. Grid 320.
// ===========================================================================
__global__ __launch_bounds__(512) void oproj4_kernel(
    const ushort* __restrict__ Xb, const int* __restrict__ QW,
    const float* __restrict__ SC, const int* __restrict__ QZ,
    float* __restrict__ Y)
{
    __shared__ __align__(16) char LDSB[65536];
    ushort* A0  = (ushort*)(LDSB);
    ushort* A1  = (ushort*)(LDSB + 16384);
    ushort* Bt0 = (ushort*)(LDSB + 32768);
    ushort* Bt1 = (ushort*)(LDSB + 49152);

    const int t  = threadIdx.x;
    const int w  = t >> 6;
    const int l  = t & 63;
    const int lg = l >> 4;
    const int lr = l & 15;
    const int wr = w >> 2;
    const int wc = w & 3;
    const int K  = NH * HD;      // 4096
    const int N  = HIDDEN;       // 2560

    const int bid = blockIdx.x;
    const int swz = (bid & 7) * 40 + (bid >> 3);   // 320 = 8*40
    const int n0  = (swz % 20) * 128;
    const int m0  = (swz / 20) * 128;

    const int am0 = t >> 3, ac0 = t & 7;
    const size_t aoff0 = (size_t)(m0 + am0) * K + (size_t)((ac0 ^ (am0 & 7)) * 8);
    const size_t aoff1 = aoff0 + (size_t)64 * K;
    const int ldsA0 = w * 1024;
    const int ldsA1 = 8192 + w * 1024;
    // B staging: 2 qwords/thread, column bn (0..127), krows bk0, bk0+1
    const int bn  = t & 127;
    const int bk0 = (t >> 7) * 2;
    int bwoff[2];
#pragma unroll
    for (int j = 0; j < 2; ++j)
        bwoff[j] = (bn * 128 + (bk0 + j) * 16) ^ ((bn & 7) << 4);

    const int xorA = (lr & 7) << 4;
    int aroff[4][2], broff[2][2];
#pragma unroll
    for (int mf = 0; mf < 4; ++mf)
#pragma unroll
        for (int ks = 0; ks < 2; ++ks)
            aroff[mf][ks] = (((wr * 64 + mf * 16 + lr) * 128) + lg * 16 + ks * 64) ^ xorA;
#pragma unroll
    for (int nf = 0; nf < 2; ++nf)
#pragma unroll
        for (int ks = 0; ks < 2; ++ks)
            broff[nf][ks] = (((wc * 32 + nf * 16 + lr) * 128) + lg * 16 + ks * 64) ^ xorA;

    f32x4 macc[4][2];
#pragma unroll
    for (int mf = 0; mf < 4; ++mf)
#pragma unroll
        for (int nf = 0; nf < 2; ++nf) macc[mf][nf] = f32x4{0.f, 0.f, 0.f, 0.f};
    uint qr[2];
    float scf, zf;

#define OP_QW(tile) { int g8 = (tile) * 8; int gg = (tile) >> 1; \
    _Pragma("unroll") \
    for (int j = 0; j < 2; ++j) \
        qr[j] = (uint)QW[(size_t)(g8 + bk0 + j) * N + n0 + bn]; \
    scf = SC[(size_t)gg * N + n0 + bn]; \
    zf  = (float)QZ[(size_t)gg * N + n0 + bn]; }

#define OP_STAGE_A(AH, k0) { \
    gl_lds16(Xb + (k0) + aoff0, (char*)(AH) + ldsA0); \
    gl_lds16(Xb + (k0) + aoff1, (char*)(AH) + ldsA1); }

#define OP_BWRITE(BT) { \
    ushort sch = f2h(scf); \
    float schf = h2f(sch); \
    ushort msc = f2h(-128.0f * schf); \
    ushort nzs = f2h(-(zf * schf)); \
    half2v S2 = {__builtin_bit_cast(_Float16, sch), __builtin_bit_cast(_Float16, sch)}; \
    half2v M2 = {__builtin_bit_cast(_Float16, msc), __builtin_bit_cast(_Float16, msc)}; \
    half2v Z2 = {__builtin_bit_cast(_Float16, nzs), __builtin_bit_cast(_Float16, nzs)}; \
    _Pragma("unroll") \
    for (int j = 0; j < 2; ++j) { \
        uint q = qr[j]; \
        uint b0 = q & 0xFFu, b1 = (q >> 8) & 0xFFu, b2 = (q >> 16) & 0xFFu, b3 = q >> 24; \
        uint e0 = 0x58005800u | ((b0 & 0xFu) << 3) | ((b0 & 0xF0u) << 15); \
        uint e1 = 0x58005800u | ((b1 & 0xFu) << 3) | ((b1 & 0xF0u) << 15); \
        uint e2 = 0x58005800u | ((b2 & 0xFu) << 3) | ((b2 & 0xF0u) << 15); \
        uint e3 = 0x58005800u | ((b3 & 0xFu) << 3) | ((b3 & 0xF0u) << 15); \
        half2v w0 = __builtin_bit_cast(half2v, e0) * S2 + M2; w0 = w0 + Z2; \
        half2v w1 = __builtin_bit_cast(half2v, e1) * S2 + M2; w1 = w1 + Z2; \
        half2v w2 = __builtin_bit_cast(half2v, e2) * S2 + M2; w2 = w2 + Z2; \
        half2v w3 = __builtin_bit_cast(half2v, e3) * S2 + M2; w3 = w3 + Z2; \
        uint4 dw = {__builtin_bit_cast(uint, w0), __builtin_bit_cast(uint, w1), \
                    __builtin_bit_cast(uint, w2), __builtin_bit_cast(uint, w3)}; \
        *(uint4*)((char*)(BT) + bwoff[j]) = dw; \
    } }

#define OP_COMPUTE(AH, BT) { \
    _Pragma("unroll") \
    for (int ks = 0; ks < 2; ++ks) { \
        half8v av[4], bv[2]; \
        _Pragma("unroll") \
        for (int mf = 0; mf < 4; ++mf) \
            av[mf] = *(const half8v*)((const char*)(AH) + aroff[mf][ks]); \
        _Pragma("unroll") \
        for (int nf = 0; nf < 2; ++nf) \
            bv[nf] = *(const half8v*)((const char*)(BT) + broff[nf][ks]); \
        _Pragma("unroll") \
        for (int mf = 0; mf < 4; ++mf) \
            _Pragma("unroll") \
            for (int nf = 0; nf < 2; ++nf) \
                macc[mf][nf] = __builtin_amdgcn_mfma_f32_16x16x32_f16(av[mf], bv[nf], macc[mf][nf], 0, 0, 0); \
    } }

    OP_QW(0);
    OP_STAGE_A(A0, 0);
    OP_BWRITE(Bt0);
    __syncthreads();

    for (int g = 0; g < 32; ++g) {
        const int t1 = 2 * g + 1;
        OP_QW(t1);
        OP_STAGE_A(A1, t1 * 64);
        OP_COMPUTE(A0, Bt0);
        OP_BWRITE(Bt1);
        __syncthreads();
        if (g < 31) {
            const int t2 = 2 * g + 2;
            OP_QW(t2);
            OP_STAGE_A(A0, t2 * 64);
        }
        OP_COMPUTE(A1, Bt1);
        if (g < 31) OP_BWRITE(Bt0);
        __syncthreads();
    }

#pragma unroll
    for (int mf = 0; mf < 4; ++mf)
#pragma unroll
        for (int r = 0; r < 4; ++r) {
            int row = m0 + wr * 64 + mf * 16 + lg * 4 + r;
#pragma unroll
            for (int nf = 0; nf < 2; ++nf)
                Y[(size_t)row * N + n0 + wc * 32 + nf * 16 + lr] = macc[mf][nf][r];
        }
#undef OP_QW
#undef OP_STAGE_A
#undef OP_BWRITE
#undef OP_COMPUTE
}

// ---------------------------------------------------------------------------
// Causal GQA flash attention, fp16 MFMA. AO out fp16.
// ---------------------------------------------------------------------------
__global__ __launch_bounds__(256) void attn_mfma_kernel(
    const ushort* __restrict__ Qh,   // [S][NH*HD] fp16, roped, *1/sqrt(HD)
    const ushort* __restrict__ Kh,   // [S][NKV*HD] fp16, roped
    const ushort* __restrict__ Vt,   // [NKV*HD][S] fp16 (transposed)
    ushort* __restrict__ AO)         // [S][NH*HD] fp16
{
    __shared__ ushort KsF[32 * 128];   // 8 KB, swz ^((row&7)<<4)
    __shared__ ushort Vs[128 * 32];    // 8 KB, swz ^((dim&3)<<4)
    __shared__ ushort Ps[4][16 * 32];  // fp16 P, swz ^((row&3)<<4)

    const int h  = blockIdx.x;
    const int qb = gridDim.y - 1 - blockIdx.y;
    const int s0 = qb * 64;
    const int t  = threadIdx.x;
    const int w  = t >> 6;
    const int l  = t & 63;
    const int lg = l >> 4;
    const int lr = l & 15;
    const int kvh = h >> 2;
    const int qw = s0 + w * 16;

    half8v qf[4];
#pragma unroll
    for (int d = 0; d < 4; ++d) {
        size_t off = (size_t)(qw + lr) * (NH * HD) + h * HD + d * 32 + lg * 8;
        qf[d] = *(const half8v*)&Qh[off];
    }

    f32x4 o[8];
#pragma unroll
    for (int i = 0; i < 8; ++i) o[i] = f32x4{0.f, 0.f, 0.f, 0.f};
    float m[4], lsum[4];
#pragma unroll
    for (int r = 0; r < 4; ++r) { m[r] = -1e30f; lsum[r] = 0.f; }

    const int ntiles = qb * 2 + 2;
    for (int kt = 0; kt < ntiles; ++kt) {
        const int k0 = kt * 32;
#pragma unroll
        for (int i = 0; i < 2; ++i) {
            int slot = w * 128 + i * 64 + l;
            int mr = slot >> 4, c = slot & 15;
            size_t goff = (size_t)(k0 + mr) * (NKV * HD) + kvh * HD + ((c ^ (mr & 7)) * 8);
            gl_lds16(Kh + goff, (char*)KsF + (w * 128 + i * 64) * 16);
        }
#pragma unroll
        for (int i = 0; i < 2; ++i) {
            int slot = w * 128 + i * 64 + l;
            int dim = slot >> 2, c = slot & 3;
            size_t goff = (size_t)(kvh * HD + dim) * S_LEN + k0 + ((c ^ (dim & 3)) * 8);
            gl_lds16(Vt + goff, (char*)Vs + (w * 128 + i * 64) * 16);
        }
        __syncthreads();

        if (k0 <= qw + 15) {
            f32x4 s[2];
            s[0] = f32x4{0.f, 0.f, 0.f, 0.f};
            s[1] = f32x4{0.f, 0.f, 0.f, 0.f};
#pragma unroll
            for (int d = 0; d < 4; ++d) {
#pragma unroll
                for (int nt2 = 0; nt2 < 2; ++nt2) {
                    int row = nt2 * 16 + lr;
                    int off = row * 256 + ((d * 64 + lg * 16) ^ ((row & 7) << 4));
                    half8v kf = *(const half8v*)((char*)KsF + off);
                    s[nt2] = __builtin_amdgcn_mfma_f32_16x16x32_f16(qf[d], kf, s[nt2], 0, 0, 0);
                }
            }
            float p0a[4], p1a[4], resc[4];
#pragma unroll
            for (int r = 0; r < 4; ++r) {
                int qrow = qw + lg * 4 + r;
                float s0v = (k0 + lr      <= qrow) ? s[0][r] : -1e30f;
                float s1v = (k0 + 16 + lr <= qrow) ? s[1][r] : -1e30f;
                float mx = fmaxf(s0v, s1v);
                mx = fmaxf(mx, __shfl_xor(mx, 1));
                mx = fmaxf(mx, __shfl_xor(mx, 2));
                mx = fmaxf(mx, __shfl_xor(mx, 4));
                mx = fmaxf(mx, __shfl_xor(mx, 8));
                float mnew = fmaxf(m[r], mx);
                resc[r] = __expf(m[r] - mnew);
                m[r] = mnew;
                float p0 = __expf(s0v - mnew);
                float p1 = __expf(s1v - mnew);
                p0a[r] = p0; p1a[r] = p1;
                float ps = p0 + p1;
                ps += __shfl_xor(ps, 1);
                ps += __shfl_xor(ps, 2);
                ps += __shfl_xor(ps, 4);
                ps += __shfl_xor(ps, 8);
                lsum[r] = lsum[r] * resc[r] + ps;
            }
#pragma unroll
            for (int dt = 0; dt < 8; ++dt)
#pragma unroll
                for (int r = 0; r < 4; ++r) o[dt][r] *= resc[r];
            ushort* pw = Ps[w];
#pragma unroll
            for (int r = 0; r < 4; ++r) {
                int row = lg * 4 + r;
                *(ushort*)((char*)pw + row * 64 + (((lr)      * 2) ^ ((row & 3) << 4))) = f2h(p0a[r]);
                *(ushort*)((char*)pw + row * 64 + (((lr + 16) * 2) ^ ((row & 3) << 4))) = f2h(p1a[r]);
            }
            asm volatile("s_waitcnt lgkmcnt(0)" ::: "memory");
            half8v pf = *(const half8v*)((char*)pw + lr * 64 + ((lg * 16) ^ ((lr & 3) << 4)));
#pragma unroll
            for (int dt = 0; dt < 8; ++dt) {
                int dim = dt * 16 + lr;
                half8v vf = *(const half8v*)((char*)Vs + dim * 64 + ((lg * 16) ^ ((dim & 3) << 4)));
                o[dt] = __builtin_amdgcn_mfma_f32_16x16x32_f16(pf, vf, o[dt], 0, 0, 0);
            }
        }
        __syncthreads();
    }

#pragma unroll
    for (int r = 0; r < 4; ++r) {
        float inv = 1.f / lsum[r];
        int qrow = qw + lg * 4 + r;
        ushort* dst = &AO[(size_t)qrow * (NH * HD) + h * HD];
#pragma unroll
        for (int dt = 0; dt < 8; ++dt) dst[dt * 16 + lr] = f2h(o[dt][r] * inv);
    }
}

// ---------------------------------------------------------------------------
extern "C" void kernel_launch(void* const* d_in, const int* in_sizes, int n_in,
                              void* d_out, int out_size, void* d_ws, size_t ws_size,
                              hipStream_t stream)
{
    const float* x    = (const float*)d_in[0];
    const float* cosb = (const float*)d_in[1];
    const float* sinb = (const float*)d_in[2];
    const float* q_sc = (const float*)d_in[3];
    const float* q_b  = (const float*)d_in[4];
    const float* k_sc = (const float*)d_in[5];
    const float* k_b  = (const float*)d_in[6];
    const float* v_sc = (const float*)d_in[7];
    const float* v_b  = (const float*)d_in[8];
    const float* o_sc = (const float*)d_in[9];
    const int* q_qw   = (const int*)d_in[10];
    const int* q_qz   = (const int*)d_in[11];
    const int* k_qw   = (const int*)d_in[12];
    const int* k_qz   = (const int*)d_in[13];
    const int* v_qw   = (const int*)d_in[14];
    const int* v_qz   = (const int*)d_in[15];
    const int* o_qw   = (const int*)d_in[16];
    const int* o_qz   = (const int*)d_in[17];
    float* out = (float*)d_out;

    // ws layout (MB):
    //   0:  Xf16 (10)  [aliased by AOf16 (16) after qkv4]
    //   16: Qf (16) | 32: Kf (4) | 36: Vrm (4) | 40: VfT (4)
    char* ws = (char*)d_ws;
    ushort* Xf   = (ushort*)ws;
    ushort* AOf  = (ushort*)ws;                                  // alias
    ushort* Qf   = (ushort*)(ws + (size_t)16 * 1024 * 1024);
    ushort* Kf   = (ushort*)(ws + (size_t)32 * 1024 * 1024);
    ushort* Vrm  = (ushort*)(ws + (size_t)36 * 1024 * 1024);
    ushort* VfT  = (ushort*)(ws + (size_t)40 * 1024 * 1024);

    xcvt_kernel<<<S_LEN, 320, 0, stream>>>(x, Xf);

    qkv4_kernel<<<384, 512, 0, stream>>>(
        Xf,
        q_qw, q_sc, q_qz, q_b,
        k_qw, k_sc, k_qz, k_b,
        v_qw, v_sc, v_qz, v_b,
        cosb, sinb, Qf, Kf, Vrm);

    vtrans_kernel<<<dim3(S_LEN / 64, (NKV * HD) / 64), 256, 0, stream>>>(Vrm, VfT);

    attn_mfma_kernel<<<dim3(NH, S_LEN / 64), 256, 0, stream>>>(Qf, Kf, VfT, AOf);

    oproj4_kernel<<<320, 512, 0, stream>>>(
        AOf, o_qw, o_sc, o_qz, out);
}

// Round 10
// 286.650 us; speedup vs baseline: 3.1836x; 1.1325x over previous
//
#include <hip/hip_runtime.h>
#include <hip/hip_bf16.h>
#include <cstdint>

#define S_LEN 2048
#define HIDDEN 2560
#define NH 32
#define NKV 8
#define HD 128
#define GS 128

typedef __attribute__((ext_vector_type(8))) _Float16 half8v;    // 8 x fp16
typedef __attribute__((ext_vector_type(2))) _Float16 half2v;    // 2 x fp16
typedef __attribute__((ext_vector_type(4))) float f32x4;
typedef unsigned int uint;
typedef unsigned short ushort;

__device__ inline ushort f2h(float f) {
    _Float16 h = (_Float16)f;
    return __builtin_bit_cast(ushort, h);
}
__device__ inline float h2f(ushort u) {
    return (float)__builtin_bit_cast(_Float16, u);
}
__device__ inline uint pk2(ushort a, ushort b) { return (uint)a | ((uint)b << 16); }

// async global->LDS, 16B per lane; lds base must be wave-uniform
__device__ __attribute__((always_inline)) inline void gl_lds16(const void* g, void* l) {
    __builtin_amdgcn_global_load_lds(
        (const __attribute__((address_space(1))) unsigned int*)g,
        (__attribute__((address_space(3))) unsigned int*)l, 16, 0, 0);
}

// ---------------------------------------------------------------------------
// X -> fp16. One block per row, 320 thr x 8 els.
// ---------------------------------------------------------------------------
__global__ __launch_bounds__(320) void xcvt_kernel(
    const float* __restrict__ X, ushort* __restrict__ Xf)
{
    const int row = blockIdx.x;
    const int t   = threadIdx.x;
    const size_t base = (size_t)row * HIDDEN + t * 8;
    float4 a = *(const float4*)&X[base];
    float4 b = *(const float4*)&X[base + 4];
    uint4 hw = {pk2(f2h(a.x), f2h(a.y)), pk2(f2h(a.z), f2h(a.w)),
                pk2(f2h(b.x), f2h(b.y)), pk2(f2h(b.z), f2h(b.w))};
    *(uint4*)&Xf[base] = hw;
}

// ===========================================================================
// Fused Q/K/V AWQ-int4 MFMA GEMM, fp16 direct-scaled B.
// B single-buffered (LDS 64 KB -> 2 blocks/CU); A double-buffered via
// global_load_lds. QW loads issued one full tile before their BWRITE.
// enc = fp16(128+nib) = 0x5800 | nib<<3 (exact);
// w = pk_fma(enc, sc_h, -128*sc_h) + (-z*sc_h).
// Block 128Mx256N, 512 thr / 8 waves (2Mx4N), wave tile 64x64.
// Wave col-remap puts RoPE partners {d, d+64} in the SAME lane.
// ===========================================================================
__global__ __launch_bounds__(512) void qkv5_kernel(
    const ushort* __restrict__ Xf,
    const int* __restrict__ q_qw, const float* __restrict__ q_sc,
    const int* __restrict__ q_qz, const float* __restrict__ q_b,
    const int* __restrict__ k_qw, const float* __restrict__ k_sc,
    const int* __restrict__ k_qz, const float* __restrict__ k_b,
    const int* __restrict__ v_qw, const float* __restrict__ v_sc,
    const int* __restrict__ v_qz, const float* __restrict__ v_b,
    const float* __restrict__ cosb, const float* __restrict__ sinb,
    ushort* __restrict__ Qf, ushort* __restrict__ Kf,
    ushort* __restrict__ Vrm)
{
    __shared__ __align__(16) char LDSB[65536];
    ushort* A0 = (ushort*)(LDSB);
    ushort* A1 = (ushort*)(LDSB + 16384);
    ushort* Bt = (ushort*)(LDSB + 32768);   // 32 KB, single buffer

    const int t  = threadIdx.x;
    const int w  = t >> 6;
    const int l  = t & 63;
    const int lg = l >> 4;
    const int lr = l & 15;
    const int wr = w >> 2;       // M half
    const int wc = w & 3;        // N quarter
    const int K  = HIDDEN;

    // XCD-bijective swizzle: 384 = 8 * 48
    const int bid = blockIdx.x;
    const int swz = (bid & 7) * 48 + (bid >> 3);
    const int nblk = swz % 24;
    const int m0   = (swz / 24) * 128;

    int region, nbase, Nw;
    const int* QW; const float* SC; const int* QZ; const float* BI;
    if (nblk < 16)      { region = 0; nbase = nblk * 256;        Nw = NH * HD;
                          QW = q_qw; SC = q_sc; QZ = q_qz; BI = q_b; }
    else if (nblk < 20) { region = 1; nbase = (nblk - 16) * 256; Nw = NKV * HD;
                          QW = k_qw; SC = k_sc; QZ = k_qz; BI = k_b; }
    else                { region = 2; nbase = (nblk - 20) * 256; Nw = NKV * HD;
                          QW = v_qw; SC = v_sc; QZ = v_qz; BI = v_b; }

    // A staging (2 chunks of 16B per thread)
    const int am0 = t >> 3, ac0 = t & 7;
    const size_t aoff0 = (size_t)(m0 + am0) * K + (size_t)((ac0 ^ (am0 & 7)) * 8);
    const size_t aoff1 = aoff0 + (size_t)64 * K;
    const int ldsA0 = w * 1024;
    const int ldsA1 = 8192 + w * 1024;
    // B staging (4 qwords per thread, one column bn, krows bk0..bk0+3)
    const int bn  = t & 255;
    const int bk0 = (t >> 8) * 4;
    int bwoff[4];
#pragma unroll
    for (int j = 0; j < 4; ++j)
        bwoff[j] = (bn * 128 + (bk0 + j) * 16) ^ ((bn & 7) << 4);

    // wave col remap (RoPE partners intra-lane)
    int ncm[4];
#pragma unroll
    for (int nf = 0; nf < 4; ++nf)
        ncm[nf] = (wc >> 1) * 128 + ((nf & 2) ? 64 : 0) + (wc & 1) * 32 + (nf & 1) * 16 + lr;

    const int xorA = (lr & 7) << 4;
    int aroff[4][2], broff[4][2];
#pragma unroll
    for (int mf = 0; mf < 4; ++mf)
#pragma unroll
        for (int ks = 0; ks < 2; ++ks)
            aroff[mf][ks] = (((wr * 64 + mf * 16 + lr) * 128) + lg * 16 + ks * 64) ^ xorA;
#pragma unroll
    for (int nf = 0; nf < 4; ++nf)
#pragma unroll
        for (int ks = 0; ks < 2; ++ks)
            broff[nf][ks] = ((ncm[nf] * 128) + lg * 16 + ks * 64) ^ xorA;

    f32x4 macc[4][4];
#pragma unroll
    for (int mf = 0; mf < 4; ++mf)
#pragma unroll
        for (int nf = 0; nf < 4; ++nf) macc[mf][nf] = f32x4{0.f, 0.f, 0.f, 0.f};
    uint qr[4];
    float scf, zf;

#define QKV_QW(tile) { int g8 = (tile) * 8; int gg = (tile) >> 1; \
    _Pragma("unroll") \
    for (int j = 0; j < 4; ++j) \
        qr[j] = (uint)QW[(size_t)(g8 + bk0 + j) * Nw + nbase + bn]; \
    scf = SC[(size_t)gg * Nw + nbase + bn]; \
    zf  = (float)QZ[(size_t)gg * Nw + nbase + bn]; }

#define QKV_STAGE_A(AH, k0) { \
    gl_lds16(Xf + (k0) + aoff0, (char*)(AH) + ldsA0); \
    gl_lds16(Xf + (k0) + aoff1, (char*)(AH) + ldsA1); }

#define QKV_BWRITE(BT) { \
    ushort sch = f2h(scf); \
    float schf = h2f(sch); \
    ushort msc = f2h(-128.0f * schf);   /* exact exponent shift */ \
    ushort nzs = f2h(-(zf * schf)); \
    half2v S2 = {__builtin_bit_cast(_Float16, sch), __builtin_bit_cast(_Float16, sch)}; \
    half2v M2 = {__builtin_bit_cast(_Float16, msc), __builtin_bit_cast(_Float16, msc)}; \
    half2v Z2 = {__builtin_bit_cast(_Float16, nzs), __builtin_bit_cast(_Float16, nzs)}; \
    _Pragma("unroll") \
    for (int j = 0; j < 4; ++j) { \
        uint q = qr[j]; \
        uint b0 = q & 0xFFu, b1 = (q >> 8) & 0xFFu, b2 = (q >> 16) & 0xFFu, b3 = q >> 24; \
        uint e0 = 0x58005800u | ((b0 & 0xFu) << 3) | ((b0 & 0xF0u) << 15); \
        uint e1 = 0x58005800u | ((b1 & 0xFu) << 3) | ((b1 & 0xF0u) << 15); \
        uint e2 = 0x58005800u | ((b2 & 0xFu) << 3) | ((b2 & 0xF0u) << 15); \
        uint e3 = 0x58005800u | ((b3 & 0xFu) << 3) | ((b3 & 0xF0u) << 15); \
        half2v w0 = __builtin_bit_cast(half2v, e0) * S2 + M2; w0 = w0 + Z2; \
        half2v w1 = __builtin_bit_cast(half2v, e1) * S2 + M2; w1 = w1 + Z2; \
        half2v w2 = __builtin_bit_cast(half2v, e2) * S2 + M2; w2 = w2 + Z2; \
        half2v w3 = __builtin_bit_cast(half2v, e3) * S2 + M2; w3 = w3 + Z2; \
        uint4 dw = {__builtin_bit_cast(uint, w0), __builtin_bit_cast(uint, w1), \
                    __builtin_bit_cast(uint, w2), __builtin_bit_cast(uint, w3)}; \
        *(uint4*)((char*)(BT) + bwoff[j]) = dw; \
    } }

#define QKV_COMPUTE(AH, BT) { \
    _Pragma("unroll") \
    for (int ks = 0; ks < 2; ++ks) { \
        half8v av[4], bv[4]; \
        _Pragma("unroll") \
        for (int mf = 0; mf < 4; ++mf) \
            av[mf] = *(const half8v*)((const char*)(AH) + aroff[mf][ks]); \
        _Pragma("unroll") \
        for (int nf = 0; nf < 4; ++nf) \
            bv[nf] = *(const half8v*)((const char*)(BT) + broff[nf][ks]); \
        _Pragma("unroll") \
        for (int mf = 0; mf < 4; ++mf) \
            _Pragma("unroll") \
            for (int nf = 0; nf < 4; ++nf) \
                macc[mf][nf] = __builtin_amdgcn_mfma_f32_16x16x32_f16(av[mf], bv[nf], macc[mf][nf], 0, 0, 0); \
    } }

    // prologue: tile 0 in Bt/A0; tile-1 QW words in flight
    QKV_QW(0);
    QKV_BWRITE(Bt);
    QKV_STAGE_A(A0, 0);
    QKV_QW(1);
    __syncthreads();

    for (int g = 0; g < 20; ++g) {
        QKV_COMPUTE(A0, Bt);                 // tile 2g
        __syncthreads();
        QKV_BWRITE(Bt);                      // tile 2g+1 (qr loaded 1 tile ago)
        QKV_STAGE_A(A1, (2 * g + 1) * 64);
        if (g < 19) QKV_QW(2 * g + 2);
        __syncthreads();
        QKV_COMPUTE(A1, Bt);                 // tile 2g+1
        __syncthreads();
        if (g < 19) {
            QKV_BWRITE(Bt);                  // tile 2g+2
            QKV_STAGE_A(A0, (2 * g + 2) * 64);
            QKV_QW(2 * g + 3);
        }
        __syncthreads();
    }

    // ---- +bias ----
#pragma unroll
    for (int nf = 0; nf < 4; ++nf) {
        float bv = BI[nbase + ncm[nf]];
#pragma unroll
        for (int mf = 0; mf < 4; ++mf)
#pragma unroll
            for (int r = 0; r < 4; ++r) macc[mf][nf][r] += bv;
    }

    // ---- epilogue ----
    if (region == 2) {
#pragma unroll
        for (int mf = 0; mf < 4; ++mf)
#pragma unroll
            for (int r = 0; r < 4; ++r) {
                int row = m0 + wr * 64 + mf * 16 + lg * 4 + r;
#pragma unroll
                for (int nf = 0; nf < 4; ++nf)
                    Vrm[(size_t)row * (NKV * HD) + nbase + ncm[nf]] = f2h(macc[mf][nf][r]);
            }
    } else {
        ushort* OF = (region == 0) ? Qf : Kf;
        const int No = (region == 0) ? NH * HD : NKV * HD;
        const float osc = (region == 0) ? 0.08838834764831845f : 1.0f;
        const int colb = nbase + (wc >> 1) * 128;
#pragma unroll
        for (int mf = 0; mf < 4; ++mf)
#pragma unroll
            for (int r = 0; r < 4; ++r) {
                int row = m0 + wr * 64 + mf * 16 + lg * 4 + r;
                const float* cb = &cosb[(size_t)row * HD];
                const float* sb = &sinb[(size_t)row * HD];
#pragma unroll
                for (int nf = 0; nf < 2; ++nf) {
                    int d = (wc & 1) * 32 + nf * 16 + lr;     // 0..63
                    float a = macc[mf][nf][r];
                    float b = macc[mf][nf + 2][r];
                    float o1 = (a * cb[d]      - b * sb[d])      * osc;
                    float o2 = (b * cb[d + 64] + a * sb[d + 64]) * osc;
                    OF[(size_t)row * No + colb + d]      = f2h(o1);
                    OF[(size_t)row * No + colb + d + 64] = f2h(o2);
                }
            }
    }
#undef QKV_QW
#undef QKV_STAGE_A
#undef QKV_BWRITE
#undef QKV_COMPUTE
}

// ---------------------------------------------------------------------------
// V transpose: Vrm [S][1024] fp16 -> VfT [1024][S]. 64x64 LDS tiles.
// ---------------------------------------------------------------------------
__global__ __launch_bounds__(256) void vtrans_kernel(
    const ushort* __restrict__ Vrm, ushort* __restrict__ VfT)
{
    __shared__ ushort Ts[64][65];
    const int s0 = blockIdx.x * 64;
    const int n0 = blockIdx.y * 64;
    const int t  = threadIdx.x;
    {
        int r = t >> 2, c0 = (t & 3) * 16;
        uint4 v0 = *(const uint4*)&Vrm[(size_t)(s0 + r) * (NKV * HD) + n0 + c0];
        uint4 v1 = *(const uint4*)&Vrm[(size_t)(s0 + r) * (NKV * HD) + n0 + c0 + 8];
        const ushort* pv = (const ushort*)&v0;
#pragma unroll
        for (int j = 0; j < 8; ++j) Ts[r][c0 + j] = pv[j];
        pv = (const ushort*)&v1;
#pragma unroll
        for (int j = 0; j < 8; ++j) Ts[r][c0 + 8 + j] = pv[j];
    }
    __syncthreads();
    {
        int rn = t >> 2, cs0 = (t & 3) * 16;
        ushort ob[16];
#pragma unroll
        for (int j = 0; j < 16; ++j) ob[j] = Ts[cs0 + j][rn];
        ushort* dst = &VfT[(size_t)(n0 + rn) * S_LEN + s0 + cs0];
        *(uint4*)dst = ((uint4*)ob)[0];
        *(uint4*)(dst + 8) = ((uint4*)ob)[1];
    }
}

// ===========================================================================
// O-projection, fp16 direct-scaled B, 2-phase dbuf (unchanged round 9).
// Block 128Mx128N, 512 thr / 8 waves, wave tile 64x32; 64 KB -> 2 blocks/CU.
// ===========================================================================
__global__ __launch_bounds__(512) void oproj4_kernel(
    const ushort* __restrict__ Xb, const int* __restrict__ QW,
    const float* __restrict__ SC, const int* __restrict__ QZ,
    float* __restrict__ Y)
{
    __shared__ __align__(16) char LDSB[65536];
    ushort* A0  = (ushort*)(LDSB);
    ushort* A1  = (ushort*)(LDSB + 16384);
    ushort* Bt0 = (ushort*)(LDSB + 32768);
    ushort* Bt1 = (ushort*)(LDSB + 49152);

    const int t  = threadIdx.x;
    const int w  = t >> 6;
    const int l  = t & 63;
    const int lg = l >> 4;
    const int lr = l & 15;
    const int wr = w >> 2;
    const int wc = w & 3;
    const int K  = NH * HD;      // 4096
    const int N  = HIDDEN;       // 2560

    const int bid = blockIdx.x;
    const int swz = (bid & 7) * 40 + (bid >> 3);   // 320 = 8*40
    const int n0  = (swz % 20) * 128;
    const int m0  = (swz / 20) * 128;

    const int am0 = t >> 3, ac0 = t & 7;
    const size_t aoff0 = (size_t)(m0 + am0) * K + (size_t)((ac0 ^ (am0 & 7)) * 8);
    const size_t aoff1 = aoff0 + (size_t)64 * K;
    const int ldsA0 = w * 1024;
    const int ldsA1 = 8192 + w * 1024;
    const int bn  = t & 127;
    const int bk0 = (t >> 7) * 2;
    int bwoff[2];
#pragma unroll
    for (int j = 0; j < 2; ++j)
        bwoff[j] = (bn * 128 + (bk0 + j) * 16) ^ ((bn & 7) << 4);

    const int xorA = (lr & 7) << 4;
    int aroff[4][2], broff[2][2];
#pragma unroll
    for (int mf = 0; mf < 4; ++mf)
#pragma unroll
        for (int ks = 0; ks < 2; ++ks)
            aroff[mf][ks] = (((wr * 64 + mf * 16 + lr) * 128) + lg * 16 + ks * 64) ^ xorA;
#pragma unroll
    for (int nf = 0; nf < 2; ++nf)
#pragma unroll
        for (int ks = 0; ks < 2; ++ks)
            broff[nf][ks] = (((wc * 32 + nf * 16 + lr) * 128) + lg * 16 + ks * 64) ^ xorA;

    f32x4 macc[4][2];
#pragma unroll
    for (int mf = 0; mf < 4; ++mf)
#pragma unroll
        for (int nf = 0; nf < 2; ++nf) macc[mf][nf] = f32x4{0.f, 0.f, 0.f, 0.f};
    uint qr[2];
    float scf, zf;

#define OP_QW(tile) { int g8 = (tile) * 8; int gg = (tile) >> 1; \
    _Pragma("unroll") \
    for (int j = 0; j < 2; ++j) \
        qr[j] = (uint)QW[(size_t)(g8 + bk0 + j) * N + n0 + bn]; \
    scf = SC[(size_t)gg * N + n0 + bn]; \
    zf  = (float)QZ[(size_t)gg * N + n0 + bn]; }

#define OP_STAGE_A(AH, k0) { \
    gl_lds16(Xb + (k0) + aoff0, (char*)(AH) + ldsA0); \
    gl_lds16(Xb + (k0) + aoff1, (char*)(AH) + ldsA1); }

#define OP_BWRITE(BT) { \
    ushort sch = f2h(scf); \
    float schf = h2f(sch); \
    ushort msc = f2h(-128.0f * schf); \
    ushort nzs = f2h(-(zf * schf)); \
    half2v S2 = {__builtin_bit_cast(_Float16, sch), __builtin_bit_cast(_Float16, sch)}; \
    half2v M2 = {__builtin_bit_cast(_Float16, msc), __builtin_bit_cast(_Float16, msc)}; \
    half2v Z2 = {__builtin_bit_cast(_Float16, nzs), __builtin_bit_cast(_Float16, nzs)}; \
    _Pragma("unroll") \
    for (int j = 0; j < 2; ++j) { \
        uint q = qr[j]; \
        uint b0 = q & 0xFFu, b1 = (q >> 8) & 0xFFu, b2 = (q >> 16) & 0xFFu, b3 = q >> 24; \
        uint e0 = 0x58005800u | ((b0 & 0xFu) << 3) | ((b0 & 0xF0u) << 15); \
        uint e1 = 0x58005800u | ((b1 & 0xFu) << 3) | ((b1 & 0xF0u) << 15); \
        uint e2 = 0x58005800u | ((b2 & 0xFu) << 3) | ((b2 & 0xF0u) << 15); \
        uint e3 = 0x58005800u | ((b3 & 0xFu) << 3) | ((b3 & 0xF0u) << 15); \
        half2v w0 = __builtin_bit_cast(half2v, e0) * S2 + M2; w0 = w0 + Z2; \
        half2v w1 = __builtin_bit_cast(half2v, e1) * S2 + M2; w1 = w1 + Z2; \
        half2v w2 = __builtin_bit_cast(half2v, e2) * S2 + M2; w2 = w2 + Z2; \
        half2v w3 = __builtin_bit_cast(half2v, e3) * S2 + M2; w3 = w3 + Z2; \
        uint4 dw = {__builtin_bit_cast(uint, w0), __builtin_bit_cast(uint, w1), \
                    __builtin_bit_cast(uint, w2), __builtin_bit_cast(uint, w3)}; \
        *(uint4*)((char*)(BT) + bwoff[j]) = dw; \
    } }

#define OP_COMPUTE(AH, BT) { \
    _Pragma("unroll") \
    for (int ks = 0; ks < 2; ++ks) { \
        half8v av[4], bv[2]; \
        _Pragma("unroll") \
        for (int mf = 0; mf < 4; ++mf) \
            av[mf] = *(const half8v*)((const char*)(AH) + aroff[mf][ks]); \
        _Pragma("unroll") \
        for (int nf = 0; nf < 2; ++nf) \
            bv[nf] = *(const half8v*)((const char*)(BT) + broff[nf][ks]); \
        _Pragma("unroll") \
        for (int mf = 0; mf < 4; ++mf) \
            _Pragma("unroll") \
            for (int nf = 0; nf < 2; ++nf) \
                macc[mf][nf] = __builtin_amdgcn_mfma_f32_16x16x32_f16(av[mf], bv[nf], macc[mf][nf], 0, 0, 0); \
    } }

    OP_QW(0);
    OP_STAGE_A(A0, 0);
    OP_BWRITE(Bt0);
    __syncthreads();

    for (int g = 0; g < 32; ++g) {
        const int t1 = 2 * g + 1;
        OP_QW(t1);
        OP_STAGE_A(A1, t1 * 64);
        OP_COMPUTE(A0, Bt0);
        OP_BWRITE(Bt1);
        __syncthreads();
        if (g < 31) {
            const int t2 = 2 * g + 2;
            OP_QW(t2);
            OP_STAGE_A(A0, t2 * 64);
        }
        OP_COMPUTE(A1, Bt1);
        if (g < 31) OP_BWRITE(Bt0);
        __syncthreads();
    }

#pragma unroll
    for (int mf = 0; mf < 4; ++mf)
#pragma unroll
        for (int r = 0; r < 4; ++r) {
            int row = m0 + wr * 64 + mf * 16 + lg * 4 + r;
#pragma unroll
            for (int nf = 0; nf < 2; ++nf)
                Y[(size_t)row * N + n0 + wc * 32 + nf * 16 + lr] = macc[mf][nf][r];
        }
#undef OP_QW
#undef OP_STAGE_A
#undef OP_BWRITE
#undef OP_COMPUTE
}

// ---------------------------------------------------------------------------
// Causal GQA flash attention, fp16 MFMA, SWAPPED operands:
//   QK: s = mfma(K, Q)  -> C col = q-row (lr), row = kv-local (lg*4+r)
//   PV: o = mfma(V, P)  -> C col = q-row (lr), row = d (lg*4+r)
// Softmax fully per-lane (each lane owns one q-row): in-reg max/sum over 8
// scores + 2 shuffles (xor 16,32). P exchanged via 80B-stride LDS rows
// (2x8B writes, 1x16B read). m/lsum scalar per lane.
// ---------------------------------------------------------------------------
__global__ __launch_bounds__(256) void attn_mfma_kernel(
    const ushort* __restrict__ Qh,   // [S][NH*HD] fp16, roped, *1/sqrt(HD)
    const ushort* __restrict__ Kh,   // [S][NKV*HD] fp16, roped
    const ushort* __restrict__ Vt,   // [NKV*HD][S] fp16 (transposed)
    ushort* __restrict__ AO)         // [S][NH*HD] fp16
{
    __shared__ ushort KsF[32 * 128];           // 8 KB, swz ^((row&7)<<4)
    __shared__ ushort Vs[128 * 32];            // 8 KB, swz ^((dim&3)<<4)
    __shared__ __align__(16) char PsB[4 * 1280];  // P: 16 rows x 80B per wave

    const int h  = blockIdx.x;
    const int qb = gridDim.y - 1 - blockIdx.y;
    const int s0 = qb * 64;
    const int t  = threadIdx.x;
    const int w  = t >> 6;
    const int l  = t & 63;
    const int lg = l >> 4;
    const int lr = l & 15;
    const int kvh = h >> 2;
    const int qw = s0 + w * 16;
    const int q  = qw + lr;          // this lane's q-row

    half8v qf[4];
#pragma unroll
    for (int d = 0; d < 4; ++d) {
        size_t off = (size_t)q * (NH * HD) + h * HD + d * 32 + lg * 8;
        qf[d] = *(const half8v*)&Qh[off];
    }

    f32x4 o[8];
#pragma unroll
    for (int i = 0; i < 8; ++i) o[i] = f32x4{0.f, 0.f, 0.f, 0.f};
    float m = -1e30f, lsum = 0.f;
    char* pw = PsB + w * 1280;

    const int ntiles = qb * 2 + 2;
    for (int kt = 0; kt < ntiles; ++kt) {
        const int k0 = kt * 32;
#pragma unroll
        for (int i = 0; i < 2; ++i) {
            int slot = w * 128 + i * 64 + l;
            int mr = slot >> 4, c = slot & 15;
            size_t goff = (size_t)(k0 + mr) * (NKV * HD) + kvh * HD + ((c ^ (mr & 7)) * 8);
            gl_lds16(Kh + goff, (char*)KsF + (w * 128 + i * 64) * 16);
        }
#pragma unroll
        for (int i = 0; i < 2; ++i) {
            int slot = w * 128 + i * 64 + l;
            int dim = slot >> 2, c = slot & 3;
            size_t goff = (size_t)(kvh * HD + dim) * S_LEN + k0 + ((c ^ (dim & 3)) * 8);
            gl_lds16(Vt + goff, (char*)Vs + (w * 128 + i * 64) * 16);
        }
        __syncthreads();

        if (k0 <= qw + 15) {   // wave-uniform causal skip
            // ---- S^T = K Q^T : C[row=kv-local][col=q] ----
            f32x4 s[2];
            s[0] = f32x4{0.f, 0.f, 0.f, 0.f};
            s[1] = f32x4{0.f, 0.f, 0.f, 0.f};
#pragma unroll
            for (int d = 0; d < 4; ++d) {
#pragma unroll
                for (int nt2 = 0; nt2 < 2; ++nt2) {
                    int row = nt2 * 16 + lr;
                    int off = row * 256 + ((d * 64 + lg * 16) ^ ((row & 7) << 4));
                    half8v kf = *(const half8v*)((char*)KsF + off);
                    s[nt2] = __builtin_amdgcn_mfma_f32_16x16x32_f16(kf, qf[d], s[nt2], 0, 0, 0);
                }
            }
            // ---- per-lane mask + online softmax (lane owns q-row) ----
            float sv[8];
#pragma unroll
            for (int nt2 = 0; nt2 < 2; ++nt2)
#pragma unroll
                for (int r = 0; r < 4; ++r) {
                    int kv = k0 + nt2 * 16 + lg * 4 + r;
                    sv[nt2 * 4 + r] = (kv <= q) ? s[nt2][r] : -1e30f;
                }
            float mx = sv[0];
#pragma unroll
            for (int j = 1; j < 8; ++j) mx = fmaxf(mx, sv[j]);
            mx = fmaxf(mx, __shfl_xor(mx, 16));
            mx = fmaxf(mx, __shfl_xor(mx, 32));
            float mnew = fmaxf(m, mx);
            float resc = __expf(m - mnew);
            m = mnew;
            float p[8], ps = 0.f;
#pragma unroll
            for (int j = 0; j < 8; ++j) { p[j] = __expf(sv[j] - mnew); ps += p[j]; }
            ps += __shfl_xor(ps, 16);
            ps += __shfl_xor(ps, 32);
            lsum = lsum * resc + ps;
#pragma unroll
            for (int dt = 0; dt < 8; ++dt)
#pragma unroll
                for (int r = 0; r < 4; ++r) o[dt][r] *= resc;
            // ---- P write: row = q-local (lr), cols kv-local ----
            uint2 w0 = {pk2(f2h(p[0]), f2h(p[1])), pk2(f2h(p[2]), f2h(p[3]))};
            uint2 w1 = {pk2(f2h(p[4]), f2h(p[5])), pk2(f2h(p[6]), f2h(p[7]))};
            *(uint2*)(pw + lr * 80 + lg * 8)      = w0;   // kv nt=0: cols lg*4..+3
            *(uint2*)(pw + lr * 80 + 32 + lg * 8) = w1;   // kv nt=1
            asm volatile("s_waitcnt lgkmcnt(0)" ::: "memory");
            // B-frag P: lane (lg,lr) -> P[q=lr][kv=lg*8..+7]
            half8v pf = *(const half8v*)(pw + lr * 80 + lg * 16);
            // ---- O += V P : C[row=d][col=q] ----
#pragma unroll
            for (int dt = 0; dt < 8; ++dt) {
                int dim = dt * 16 + lr;
                half8v vf = *(const half8v*)((char*)Vs + dim * 64 + ((lg * 16) ^ ((dim & 3) << 4)));
                o[dt] = __builtin_amdgcn_mfma_f32_16x16x32_f16(vf, pf, o[dt], 0, 0, 0);
            }
        }
        __syncthreads();
    }

    // ---- epilogue: lane owns q-row; d = dt*16 + lg*4 + r ----
    float inv = 1.f / lsum;
    ushort* dst = &AO[(size_t)q * (NH * HD) + h * HD];
#pragma unroll
    for (int dt = 0; dt < 8; ++dt) {
        uint2 ov = {pk2(f2h(o[dt][0] * inv), f2h(o[dt][1] * inv)),
                    pk2(f2h(o[dt][2] * inv), f2h(o[dt][3] * inv))};
        *(uint2*)(dst + dt * 16 + lg * 4) = ov;
    }
}

// ---------------------------------------------------------------------------
extern "C" void kernel_launch(void* const* d_in, const int* in_sizes, int n_in,
                              void* d_out, int out_size, void* d_ws, size_t ws_size,
                              hipStream_t stream)
{
    const float* x    = (const float*)d_in[0];
    const float* cosb = (const float*)d_in[1];
    const float* sinb = (const float*)d_in[2];
    const float* q_sc = (const float*)d_in[3];
    const float* q_b  = (const float*)d_in[4];
    const float* k_sc = (const float*)d_in[5];
    const float* k_b  = (const float*)d_in[6];
    const float* v_sc = (const float*)d_in[7];
    const float* v_b  = (const float*)d_in[8];
    const float* o_sc = (const float*)d_in[9];
    const int* q_qw   = (const int*)d_in[10];
    const int* q_qz   = (const int*)d_in[11];
    const int* k_qw   = (const int*)d_in[12];
    const int* k_qz   = (const int*)d_in[13];
    const int* v_qw   = (const int*)d_in[14];
    const int* v_qz   = (const int*)d_in[15];
    const int* o_qw   = (const int*)d_in[16];
    const int* o_qz   = (const int*)d_in[17];
    float* out = (float*)d_out;

    // ws layout (MB):
    //   0:  Xf16 (10)  [aliased by AOf16 (16) after qkv5]
    //   16: Qf (16) | 32: Kf (4) | 36: Vrm (4) | 40: VfT (4)
    char* ws = (char*)d_ws;
    ushort* Xf   = (ushort*)ws;
    ushort* AOf  = (ushort*)ws;                                  // alias
    ushort* Qf   = (ushort*)(ws + (size_t)16 * 1024 * 1024);
    ushort* Kf   = (ushort*)(ws + (size_t)32 * 1024 * 1024);
    ushort* Vrm  = (ushort*)(ws + (size_t)36 * 1024 * 1024);
    ushort* VfT  = (ushort*)(ws + (size_t)40 * 1024 * 1024);

    xcvt_kernel<<<S_LEN, 320, 0, stream>>>(x, Xf);

    qkv5_kernel<<<384, 512, 0, stream>>>(
        Xf,
        q_qw, q_sc, q_qz, q_b,
        k_qw, k_sc, k_qz, k_b,
        v_qw, v_sc, v_qz, v_b,
        cosb, sinb, Qf, Kf, Vrm);

    vtrans_kernel<<<dim3(S_LEN / 64, (NKV * HD) / 64), 256, 0, stream>>>(Vrm, VfT);

    attn_mfma_kernel<<<dim3(NH, S_LEN / 64), 256, 0, stream>>>(Qf, Kf, VfT, AOf);

    oproj4_kernel<<<320, 512, 0, stream>>>(
        AOf, o_qw, o_sc, o_qz, out);
}